// Round 2
// baseline (1066.425 us; speedup 1.0000x reference)
//
#include <hip/hip_runtime.h>
#include <hip/hip_bf16.h>

// Problem constants
#define NC   8192
#define EC   131072
#define DC   128
#define TC   8
#define P0C  512
#define P1C  128
#define ZIC  120
#define TEMPC 200.0f
// atanh(float32(1 - 1e-5)) = atanh(0.99999004602432251) -- matches JAX's f32 clip
#define ATANH_MAX 6.1053405f

// ---------------------------------------------------------------------------
// Tiled f32 GEMM:  C[M,N] = A[M,K](lda) @ B[K,N](ldb) + bias  (bias optional)
// ---------------------------------------------------------------------------
__global__ __launch_bounds__(256) void k_gemm_nn(
    const float* __restrict__ A, int lda,
    const float* __restrict__ B, int ldb,
    const float* __restrict__ bias,
    float* __restrict__ C, int ldc,
    int M, int N, int K)
{
  __shared__ float As[16][65];
  __shared__ float Bs[16][65];
  int bm = blockIdx.x * 64, bn = blockIdx.y * 64;
  int tid = threadIdx.x;
  int tm = (tid >> 4) << 2, tn = (tid & 15) << 2;
  float acc[4][4] = {};
  for (int k0 = 0; k0 < K; k0 += 16) {
    for (int i = tid; i < 1024; i += 256) {
      int m = i >> 4, k = i & 15;
      float v = 0.f;
      if (bm + m < M && k0 + k < K) v = A[(size_t)(bm + m) * lda + k0 + k];
      As[k][m] = v;
    }
    for (int i = tid; i < 1024; i += 256) {
      int k = i >> 6, n = i & 63;
      float v = 0.f;
      if (k0 + k < K && bn + n < N) v = B[(size_t)(k0 + k) * ldb + bn + n];
      Bs[k][n] = v;
    }
    __syncthreads();
#pragma unroll
    for (int kk = 0; kk < 16; ++kk) {
      float a[4], b[4];
#pragma unroll
      for (int i = 0; i < 4; i++) a[i] = As[kk][tm + i];
#pragma unroll
      for (int j = 0; j < 4; j++) b[j] = Bs[kk][tn + j];
#pragma unroll
      for (int i = 0; i < 4; i++)
#pragma unroll
        for (int j = 0; j < 4; j++) acc[i][j] += a[i] * b[j];
    }
    __syncthreads();
  }
#pragma unroll
  for (int i = 0; i < 4; i++) {
    int m = bm + tm + i; if (m >= M) continue;
#pragma unroll
    for (int j = 0; j < 4; j++) {
      int n = bn + tn + j; if (n >= N) continue;
      float v = acc[i][j];
      if (bias) v += bias[n];
      C[(size_t)m * ldc + n] = v;
    }
  }
}

// ---------------------------------------------------------------------------
// Transposed-A GEMM with split-K + atomic accumulate:
//   C[M,N] += (A[K,M](lda))^T @ B[K,N](ldb)   for k in [z*kchunk, ...)
// C must be zeroed before the first launch.
// ---------------------------------------------------------------------------
__global__ __launch_bounds__(256) void k_gemm_tn(
    const float* __restrict__ A, int lda,
    const float* __restrict__ B, int ldb,
    float* __restrict__ C, int ldc,
    int M, int N, int K, int kchunk)
{
  __shared__ float As[16][65];
  __shared__ float Bs[16][65];
  int bm = blockIdx.x * 64, bn = blockIdx.y * 64;
  int ks = blockIdx.z * kchunk;
  int ke = min(K, ks + kchunk);
  int tid = threadIdx.x;
  int tm = (tid >> 4) << 2, tn = (tid & 15) << 2;
  float acc[4][4] = {};
  for (int k0 = ks; k0 < ke; k0 += 16) {
    for (int i = tid; i < 1024; i += 256) {
      int k = i >> 6, m = i & 63;
      float v = 0.f;
      if (k0 + k < ke && bm + m < M) v = A[(size_t)(k0 + k) * lda + bm + m];
      As[k][m] = v;
    }
    for (int i = tid; i < 1024; i += 256) {
      int k = i >> 6, n = i & 63;
      float v = 0.f;
      if (k0 + k < ke && bn + n < N) v = B[(size_t)(k0 + k) * ldb + bn + n];
      Bs[k][n] = v;
    }
    __syncthreads();
#pragma unroll
    for (int kk = 0; kk < 16; ++kk) {
      float a[4], b[4];
#pragma unroll
      for (int i = 0; i < 4; i++) a[i] = As[kk][tm + i];
#pragma unroll
      for (int j = 0; j < 4; j++) b[j] = Bs[kk][tn + j];
#pragma unroll
      for (int i = 0; i < 4; i++)
#pragma unroll
        for (int j = 0; j < 4; j++) acc[i][j] += a[i] * b[j];
    }
    __syncthreads();
  }
#pragma unroll
  for (int i = 0; i < 4; i++) {
    int m = bm + tm + i; if (m >= M) continue;
#pragma unroll
    for (int j = 0; j < 4; j++) {
      int n = bn + tn + j; if (n >= N) continue;
      atomicAdd(&C[(size_t)m * ldc + n], acc[i][j]);
    }
  }
}

// ---------------------------------------------------------------------------
// CSR build
// ---------------------------------------------------------------------------
__global__ void k_count(const int* __restrict__ adj, int* __restrict__ counts)
{
  int e = blockIdx.x * 256 + threadIdx.x;
  if (e < EC) atomicAdd(&counts[adj[e]], 1);
}

__global__ __launch_bounds__(1024) void k_scan(const int* __restrict__ counts,
                                               int* __restrict__ offsets)
{
  __shared__ int tsum[1024];
  int tid = threadIdx.x;
  int base = tid * 8;
  int loc[8]; int s = 0;
#pragma unroll
  for (int i = 0; i < 8; i++) { loc[i] = s; s += counts[base + i]; }
  tsum[tid] = s;
  __syncthreads();
  for (int off = 1; off < 1024; off <<= 1) {
    int v = (tid >= off) ? tsum[tid - off] : 0;
    __syncthreads();
    tsum[tid] += v;
    __syncthreads();
  }
  int excl = (tid == 0) ? 0 : tsum[tid - 1];
#pragma unroll
  for (int i = 0; i < 8; i++) offsets[base + i] = excl + loc[i];
  if (tid == 1023) offsets[NC] = tsum[1023];
}

__global__ void k_scatter(const int* __restrict__ adj, const int* __restrict__ offsets,
                          int* __restrict__ fill, int* __restrict__ csr)
{
  int e = blockIdx.x * 256 + threadIdx.x;
  if (e < EC) {
    int d = adj[e], s = adj[EC + e];
    int p = atomicAdd(&fill[d], 1);
    csr[offsets[d] + p] = s;
  }
}

// ---------------------------------------------------------------------------
// Level-0 aggregation (WITH edge multiplicity):
//   sAgg[j,:] = sum_e sPre[src,:] ;  z[j,8:] = sum_e t0[src,:] ; z[j,:8]=x[j,:8]
// ---------------------------------------------------------------------------
__global__ __launch_bounds__(256) void k_agg0(
    const int* __restrict__ offsets, const int* __restrict__ csr,
    const float* __restrict__ sPre, const float* __restrict__ t0,
    const float* __restrict__ x,
    float* __restrict__ sAgg, float* __restrict__ z)
{
  int j = blockIdx.x;
  int beg = offsets[j], deg = offsets[j + 1] - beg;
  __shared__ int srcs[1024];
  bool inl = (deg <= 1024);
  if (inl) for (int i = threadIdx.x; i < deg; i += 256) srcs[i] = csr[beg + i];
  __syncthreads();
  for (int c = threadIdx.x; c < P0C; c += 256) {
    float acc = 0.f;
    for (int i = 0; i < deg; i++) {
      int s = inl ? srcs[i] : csr[beg + i];
      acc += sPre[(size_t)s * P0C + c];
    }
    sAgg[(size_t)j * P0C + c] = acc;
  }
  for (int c = threadIdx.x; c < ZIC; c += 256) {
    float acc = 0.f;
    for (int i = 0; i < deg; i++) {
      int s = inl ? srcs[i] : csr[beg + i];
      acc += t0[(size_t)s * ZIC + c];
    }
    z[(size_t)j * DC + 8 + c] = acc;
  }
  if (threadIdx.x < 8) z[(size_t)j * DC + threadIdx.x] = x[(size_t)j * DC + threadIdx.x];
}

// ---------------------------------------------------------------------------
// M = A0_dedup @ S0  (duplicate (dest,src) edges count once)
// ---------------------------------------------------------------------------
__global__ __launch_bounds__(256) void k_aggM(
    const int* __restrict__ offsets, const int* __restrict__ csr,
    const float* __restrict__ S0, float* __restrict__ M)
{
  int j = blockIdx.x;
  int beg = offsets[j], deg = offsets[j + 1] - beg;
  __shared__ int srcs[1024];
  bool inl = (deg <= 1024);
  if (inl) for (int i = threadIdx.x; i < deg; i += 256) srcs[i] = csr[beg + i];
  __syncthreads();
  if (inl) {
    for (int t = threadIdx.x; t < deg; t += 256) {
      int v = srcs[t];
      for (int u = 0; u < t; ++u)
        if (csr[beg + u] == v) { srcs[t] = -1; break; }
    }
  }
  __syncthreads();
  for (int c = threadIdx.x; c < P0C; c += 256) {
    float acc = 0.f;
    for (int i = 0; i < deg; i++) {
      int s = inl ? srcs[i] : csr[beg + i];
      if (!inl) {
        bool dup = false;
        for (int u = 0; u < i; u++) if (csr[beg + u] == s) { dup = true; break; }
        if (dup) s = -1;
      }
      if (s >= 0) acc += S0[(size_t)s * P0C + c];
    }
    M[(size_t)j * P0C + c] = acc;
  }
}

// ---------------------------------------------------------------------------
// Fused expmap0/logmap0 row scale: rs[r] = TEMP * min(||u||, ATANH_MAX)/||u||
// ---------------------------------------------------------------------------
__global__ __launch_bounds__(256) void k_rowscale(const float* __restrict__ U, int cols,
                                                  float* __restrict__ rs)
{
  int r = blockIdx.x;
  const float* row = U + (size_t)r * cols;
  float ss = 0.f;
  for (int c = threadIdx.x; c < cols; c += 256) { float v = row[c]; ss += v * v; }
  for (int off = 32; off > 0; off >>= 1) ss += __shfl_down(ss, off);
  __shared__ float red[4];
  if ((threadIdx.x & 63) == 0) red[threadIdx.x >> 6] = ss;
  __syncthreads();
  if (threadIdx.x == 0) {
    float n = sqrtf(red[0] + red[1] + red[2] + red[3]);
    n = fmaxf(n, 1e-15f);
    rs[r] = TEMPC * fminf(n, ATANH_MAX) / n;
  }
}

// ---------------------------------------------------------------------------
// Column softmax (axis=0) over rows, logits l = rs[r]*U[r,c]; two-stage online
// ---------------------------------------------------------------------------
__global__ __launch_bounds__(256) void k_smaxA(const float* __restrict__ U,
    const float* __restrict__ rs, float* __restrict__ pm, float* __restrict__ ps,
    int rows, int cols, int rpg)
{
  int lc = threadIdx.x & 63;
  int c = blockIdx.x * 64 + lc;
  int rl = threadIdx.x >> 6;
  int r0 = blockIdx.y * rpg, r1 = min(rows, r0 + rpg);
  float m = -1e30f, s = 0.f;
  for (int r = r0 + rl; r < r1; r += 4) {
    float l = rs[r] * U[(size_t)r * cols + c];
    if (l > m) { s = s * __expf(m - l) + 1.f; m = l; }
    else s += __expf(l - m);
  }
  __shared__ float sm[4][64], sv[4][64];
  sm[rl][lc] = m; sv[rl][lc] = s;
  __syncthreads();
  if (threadIdx.x < 64) {
    float mm = sm[0][threadIdx.x], s2 = sv[0][threadIdx.x];
    for (int q = 1; q < 4; q++) {
      float mq = sm[q][threadIdx.x], sq = sv[q][threadIdx.x];
      float mn = fmaxf(mm, mq);
      s2 = s2 * __expf(mm - mn) + sq * __expf(mq - mn);
      mm = mn;
    }
    pm[(size_t)blockIdx.y * cols + blockIdx.x * 64 + threadIdx.x] = mm;
    ps[(size_t)blockIdx.y * cols + blockIdx.x * 64 + threadIdx.x] = s2;
  }
}

__global__ void k_smaxB(const float* __restrict__ pm, const float* __restrict__ ps,
                        float* __restrict__ colm, float* __restrict__ colsum,
                        int ng, int cols)
{
  int c = blockIdx.x * blockDim.x + threadIdx.x;
  if (c >= cols) return;
  float m = -1e30f, s = 0.f;
  for (int g = 0; g < ng; g++) {
    float mg = pm[(size_t)g * cols + c], sg = ps[(size_t)g * cols + c];
    float mn = fmaxf(m, mg);
    s = s * __expf(m - mn) + sg * __expf(mg - mn);
    m = mn;
  }
  colm[c] = m; colsum[c] = s;
}

__global__ __launch_bounds__(256) void k_smaxC(const float* __restrict__ U,
    const float* __restrict__ rs, const float* __restrict__ colm,
    const float* __restrict__ colsum, float* __restrict__ S,
    float* __restrict__ loss, int rows, int cols, int rpg)
{
  int lc = threadIdx.x & 63;
  int c = blockIdx.x * 64 + lc;
  int rl = threadIdx.x >> 6;
  int r0 = blockIdx.y * rpg, r1 = min(rows, r0 + rpg);
  float m = colm[c], inv = 1.f / colsum[c];
  float h = 0.f;
  for (int r = r0 + rl; r < r1; r += 4) {
    float l = rs[r] * U[(size_t)r * cols + c];
    float p = __expf(l - m) * inv;
    S[(size_t)r * cols + c] = p;
    if (p > 0.f) h -= p * __logf(p);
  }
  for (int off = 32; off > 0; off >>= 1) h += __shfl_down(h, off);
  __shared__ float red[4];
  if ((threadIdx.x & 63) == 0) red[threadIdx.x >> 6] = h;
  __syncthreads();
  if (threadIdx.x == 0) atomicAdd(loss, red[0] + red[1] + red[2] + red[3]);
}

// single-stage small column softmax (level 1: 512 rows)
__global__ __launch_bounds__(256) void k_smax_small(const float* __restrict__ U,
    const float* __restrict__ rs, float* __restrict__ S, float* __restrict__ loss,
    int rows, int cols)
{
  int lc = threadIdx.x & 63;
  int c = blockIdx.x * 64 + lc;
  int rl = threadIdx.x >> 6;
  float m = -1e30f, s = 0.f;
  for (int r = rl; r < rows; r += 4) {
    float l = rs[r] * U[(size_t)r * cols + c];
    if (l > m) { s = s * __expf(m - l) + 1.f; m = l; }
    else s += __expf(l - m);
  }
  __shared__ float sm[4][64], sv[4][64], fm[64], fs[64];
  sm[rl][lc] = m; sv[rl][lc] = s;
  __syncthreads();
  if (threadIdx.x < 64) {
    float mm = sm[0][threadIdx.x], s2 = sv[0][threadIdx.x];
    for (int q = 1; q < 4; q++) {
      float mq = sm[q][threadIdx.x], sq = sv[q][threadIdx.x];
      float mn = fmaxf(mm, mq);
      s2 = s2 * __expf(mm - mn) + sq * __expf(mq - mn);
      mm = mn;
    }
    fm[threadIdx.x] = mm; fs[threadIdx.x] = s2;
  }
  __syncthreads();
  float M0 = fm[lc], inv = 1.f / fs[lc];
  float h = 0.f;
  for (int r = rl; r < rows; r += 4) {
    float l = rs[r] * U[(size_t)r * cols + c];
    float p = __expf(l - M0) * inv;
    S[(size_t)r * cols + c] = p;
    if (p > 0.f) h -= p * __logf(p);
  }
  for (int off = 32; off > 0; off >>= 1) h += __shfl_down(h, off);
  if ((threadIdx.x & 63) == 0) atomicAdd(loss, h);
}

// ---------------------------------------------------------------------------
// y-projections: out[t,c] += sum_k Y[t,k] * S[k,c]   (T=8 fixed)
// ---------------------------------------------------------------------------
__global__ __launch_bounds__(256) void k_yS(const float* __restrict__ Y, int ldy,
    const float* __restrict__ S, int ldS, float* __restrict__ outp, int ldo,
    int K, int C, int kchunk)
{
  int c = blockIdx.x * 256 + threadIdx.x;
  if (c >= C) return;
  int k0 = blockIdx.y * kchunk, k1 = min(K, k0 + kchunk);
  float acc[8] = {};
  for (int k = k0; k < k1; ++k) {
    float sv = S[(size_t)k * ldS + c];
#pragma unroll
    for (int t = 0; t < 8; t++) acc[t] += Y[(size_t)t * ldy + k] * sv;
  }
#pragma unroll
  for (int t = 0; t < 8; t++) atomicAdd(&outp[(size_t)t * ldo + c], acc[t]);
}

__global__ void k_zbuild1(const float* __restrict__ x1f, const float* __restrict__ zi1,
                          float* __restrict__ z1)
{
  int idx = blockIdx.x * 256 + threadIdx.x;
  if (idx >= P0C * DC) return;
  int r = idx >> 7, c = idx & 127;
  z1[idx] = (c < 8) ? x1f[idx] : zi1[r * ZIC + c - 8];
}

// f32 -> f32 copy/emit with independent src/dst leading dims
__global__ void k_emit(const float* __restrict__ src, int lsrc,
                       float* __restrict__ dst, int ldd, int rows, int cols)
{
  int idx = blockIdx.x * 256 + threadIdx.x;
  if (idx >= rows * cols) return;
  int r = idx / cols, c = idx - r * cols;
  dst[(size_t)r * ldd + c] = src[(size_t)r * lsrc + c];
}

// ---------------------------------------------------------------------------
extern "C" void kernel_launch(void* const* d_in, const int* in_sizes, int n_in,
                              void* d_out, int out_size, void* d_ws, size_t ws_size,
                              hipStream_t stream)
{
  (void)in_sizes; (void)n_in; (void)out_size; (void)ws_size;
  const float* x   = (const float*)d_in[0];
  const float* y   = (const float*)d_in[1];
  const float* We0 = (const float*)d_in[2];
  const float* be0 = (const float*)d_in[3];
  const float* Ws0 = (const float*)d_in[4];
  const float* bs0 = (const float*)d_in[5];
  const float* We1 = (const float*)d_in[6];
  const float* be1 = (const float*)d_in[7];
  const float* Ws1 = (const float*)d_in[8];
  const float* bs1 = (const float*)d_in[9];
  const int*   adj = (const int*)d_in[10];
  float* out = (float*)d_out;

  float* ws = (float*)d_ws;
  size_t o = 0;
  auto alloc = [&](size_t n) { float* p = ws + o; o += n; return p; };
  float* t0    = alloc((size_t)NC * ZIC);
  float* sPre  = alloc((size_t)NC * P0C);   // reused as S0 after softmax
  float* sAgg  = alloc((size_t)NC * P0C);   // reused as M after softmax
  float* zbuf  = alloc((size_t)NC * DC);
  float* rsc   = alloc(NC);
  float* pm    = alloc(32 * P0C);
  float* ps    = alloc(32 * P0C);
  float* colm  = alloc(P0C);
  float* colsum= alloc(P0C);
  float* t1    = alloc((size_t)P0C * ZIC);
  float* s1pre = alloc((size_t)P0C * P1C);
  float* zi1   = alloc((size_t)P0C * ZIC);
  float* s1agg = alloc((size_t)P0C * P1C);
  float* S1    = alloc((size_t)P0C * P1C);
  float* z1    = alloc((size_t)P0C * P1C);
  float* rs1   = alloc(P0C);
  // atomic-accumulated region (must be zeroed every call)
  float* x1f   = alloc((size_t)P0C * DC);
  float* A1    = alloc((size_t)P0C * P0C);
  float* x2f   = alloc((size_t)P1C * DC);
  float* y1f   = alloc((size_t)TC * P0C);
  float* y2f   = alloc((size_t)TC * P1C);
  float* lossf = alloc(1);
  size_t atomicFloats = (size_t)P0C*DC + (size_t)P0C*P0C + (size_t)P1C*DC
                      + (size_t)TC*P0C + (size_t)TC*P1C + 1;
  o = (o + 63) & ~(size_t)63;
  int* ibase   = (int*)(ws + o);
  int* counts  = ibase;
  int* fill    = ibase + NC;
  int* offsets = ibase + 2 * NC;
  int* csr     = ibase + 2 * NC + (NC + 1);

  float* S0 = sPre;   // alias: sPre dead after k_agg0
  float* Mb = sAgg;   // alias: sAgg dead after k_smaxC

  hipMemsetAsync(x1f, 0, atomicFloats * sizeof(float), stream);
  hipMemsetAsync(counts, 0, 2 * NC * sizeof(int), stream);

  // ---- level 0 transforms ----
  k_gemm_nn<<<dim3(NC/64, (ZIC+63)/64), 256, 0, stream>>>(x + 8, DC, We0, ZIC, be0, t0, ZIC, NC, ZIC, ZIC);
  k_gemm_nn<<<dim3(NC/64, P0C/64), 256, 0, stream>>>(x, DC, Ws0, P0C, bs0, sPre, P0C, NC, P0C, DC);

  // ---- CSR build ----
  k_count  <<<EC/256, 256, 0, stream>>>(adj, counts);
  k_scan   <<<1, 1024, 0, stream>>>(counts, offsets);
  k_scatter<<<EC/256, 256, 0, stream>>>(adj, offsets, fill, csr);

  // ---- aggregation (with multiplicity) + z assembly ----
  k_agg0<<<NC, 256, 0, stream>>>(offsets, csr, sPre, t0, x, sAgg, zbuf);

  // ---- fused expmap/logmap + column softmax -> S0, entropy ----
  k_rowscale<<<NC, 256, 0, stream>>>(sAgg, P0C, rsc);
  k_smaxA<<<dim3(P0C/64, 32), 256, 0, stream>>>(sAgg, rsc, pm, ps, NC, P0C, 256);
  k_smaxB<<<P0C/256, 256, 0, stream>>>(pm, ps, colm, colsum, 32, P0C);
  k_smaxC<<<dim3(P0C/64, 32), 256, 0, stream>>>(sAgg, rsc, colm, colsum, S0, lossf, NC, P0C, 256);

  // ---- M = A0_dedup @ S0 ; pooled products ----
  k_aggM<<<NC, 256, 0, stream>>>(offsets, csr, S0, Mb);
  k_gemm_tn<<<dim3(P0C/64, DC/64, 32), 256, 0, stream>>>(S0, P0C, zbuf, DC, x1f, DC, P0C, DC, NC, 256);
  k_gemm_tn<<<dim3(P0C/64, P0C/64, 8), 256, 0, stream>>>(S0, P0C, Mb, P0C, A1, P0C, P0C, P0C, NC, 1024);
  k_yS<<<dim3(P0C/256, 16), 256, 0, stream>>>(y, NC, S0, P0C, y1f, P0C, NC, P0C, NC/16);

  // ---- level 1 ----
  k_gemm_nn<<<dim3(P0C/64, (ZIC+63)/64), 256, 0, stream>>>(x1f + 8, DC, We1, ZIC, be1, t1, ZIC, P0C, ZIC, ZIC);
  k_gemm_nn<<<dim3(P0C/64, P1C/64), 256, 0, stream>>>(x1f, DC, Ws1, P1C, bs1, s1pre, P1C, P0C, P1C, DC);
  k_gemm_nn<<<dim3(P0C/64, (ZIC+63)/64), 256, 0, stream>>>(A1, P0C, t1, ZIC, nullptr, zi1, ZIC, P0C, ZIC, P0C);
  k_gemm_nn<<<dim3(P0C/64, P1C/64), 256, 0, stream>>>(A1, P0C, s1pre, P1C, nullptr, s1agg, P1C, P0C, P1C, P0C);
  k_zbuild1<<<(P0C*DC + 255)/256, 256, 0, stream>>>(x1f, zi1, z1);
  k_rowscale<<<P0C, 256, 0, stream>>>(s1agg, P1C, rs1);
  k_smax_small<<<P1C/64, 256, 0, stream>>>(s1agg, rs1, S1, lossf, P0C, P1C);
  k_gemm_tn<<<dim3(P1C/64, DC/64, 4), 256, 0, stream>>>(S1, P1C, z1, DC, x2f, DC, P1C, DC, P0C, 128);
  k_yS<<<dim3(1, 4), 256, 0, stream>>>(y1f, P0C, S1, P1C, y2f, P1C, P0C, P1C, P0C/4);

  // ---- emit outputs (f32) ----
  const size_t yr_off = (size_t)(NC + P0C + P1C) * DC;  // 1130496
  const int YW = NC + P0C + P1C;                        // 8832
  k_emit<<<(NC*DC + 255)/256, 256, 0, stream>>>(x, DC, out, DC, NC, DC);
  k_emit<<<(P0C*DC + 255)/256, 256, 0, stream>>>(x1f, DC, out + (size_t)NC*DC, DC, P0C, DC);
  k_emit<<<(P1C*DC + 255)/256, 256, 0, stream>>>(x2f, DC, out + (size_t)(NC+P0C)*DC, DC, P1C, DC);
  k_emit<<<(TC*NC + 255)/256, 256, 0, stream>>>(y, NC, out + yr_off, YW, TC, NC);
  k_emit<<<(TC*P0C + 255)/256, 256, 0, stream>>>(y1f, P0C, out + yr_off + NC, YW, TC, P0C);
  k_emit<<<(TC*P1C + 255)/256, 256, 0, stream>>>(y2f, P1C, out + yr_off + NC + P0C, YW, TC, P1C);
  k_emit<<<1, 256, 0, stream>>>(lossf, 1, out + yr_off + (size_t)TC*YW, 1, 1, 1);
}

// Round 3
// 824.907 us; speedup vs baseline: 1.2928x; 1.2928x over previous
//
#include <hip/hip_runtime.h>
#include <hip/hip_bf16.h>

// Problem constants
#define NC   8192
#define EC   131072
#define DC   128
#define TC   8
#define P0C  512
#define P1C  128
#define ZIC  120
#define TEMPC 200.0f
// atanh(float32(1 - 1e-5)) = atanh(0.99999004602432251) -- matches JAX's f32 clip
#define ATANH_MAX 6.1053405f

typedef short short8 __attribute__((ext_vector_type(8)));
typedef float f32x4 __attribute__((ext_vector_type(4)));

__device__ inline unsigned short f2b(float f) {  // f32 -> bf16 bits, RNE
  union { float f; unsigned u; } x; x.f = f;
  unsigned r = x.u + 0x7FFFu + ((x.u >> 16) & 1u);
  return (unsigned short)(r >> 16);
}

// ---------------------------------------------------------------------------
// Tiled f32 GEMM:  C[M,N] = A[M,K](lda) @ B[K,N](ldb) + bias  (bias optional)
// ---------------------------------------------------------------------------
__global__ __launch_bounds__(256) void k_gemm_nn(
    const float* __restrict__ A, int lda,
    const float* __restrict__ B, int ldb,
    const float* __restrict__ bias,
    float* __restrict__ C, int ldc,
    int M, int N, int K)
{
  __shared__ float As[16][65];
  __shared__ float Bs[16][65];
  int bm = blockIdx.x * 64, bn = blockIdx.y * 64;
  int tid = threadIdx.x;
  int tm = (tid >> 4) << 2, tn = (tid & 15) << 2;
  float acc[4][4] = {};
  for (int k0 = 0; k0 < K; k0 += 16) {
    for (int i = tid; i < 1024; i += 256) {
      int m = i >> 4, k = i & 15;
      float v = 0.f;
      if (bm + m < M && k0 + k < K) v = A[(size_t)(bm + m) * lda + k0 + k];
      As[k][m] = v;
    }
    for (int i = tid; i < 1024; i += 256) {
      int k = i >> 6, n = i & 63;
      float v = 0.f;
      if (k0 + k < K && bn + n < N) v = B[(size_t)(k0 + k) * ldb + bn + n];
      Bs[k][n] = v;
    }
    __syncthreads();
#pragma unroll
    for (int kk = 0; kk < 16; ++kk) {
      float a[4], b[4];
#pragma unroll
      for (int i = 0; i < 4; i++) a[i] = As[kk][tm + i];
#pragma unroll
      for (int j = 0; j < 4; j++) b[j] = Bs[kk][tn + j];
#pragma unroll
      for (int i = 0; i < 4; i++)
#pragma unroll
        for (int j = 0; j < 4; j++) acc[i][j] += a[i] * b[j];
    }
    __syncthreads();
  }
#pragma unroll
  for (int i = 0; i < 4; i++) {
    int m = bm + tm + i; if (m >= M) continue;
#pragma unroll
    for (int j = 0; j < 4; j++) {
      int n = bn + tn + j; if (n >= N) continue;
      float v = acc[i][j];
      if (bias) v += bias[n];
      C[(size_t)m * ldc + n] = v;
    }
  }
}

// ---------------------------------------------------------------------------
// Small f32 TN GEMM with split-K + atomics (kept for the tiny x2 product)
// ---------------------------------------------------------------------------
__global__ __launch_bounds__(256) void k_gemm_tn(
    const float* __restrict__ A, int lda,
    const float* __restrict__ B, int ldb,
    float* __restrict__ C, int ldc,
    int M, int N, int K, int kchunk)
{
  __shared__ float As[16][65];
  __shared__ float Bs[16][65];
  int bm = blockIdx.x * 64, bn = blockIdx.y * 64;
  int ks = blockIdx.z * kchunk;
  int ke = min(K, ks + kchunk);
  int tid = threadIdx.x;
  int tm = (tid >> 4) << 2, tn = (tid & 15) << 2;
  float acc[4][4] = {};
  for (int k0 = ks; k0 < ke; k0 += 16) {
    for (int i = tid; i < 1024; i += 256) {
      int k = i >> 6, m = i & 63;
      float v = 0.f;
      if (k0 + k < ke && bm + m < M) v = A[(size_t)(k0 + k) * lda + bm + m];
      As[k][m] = v;
    }
    for (int i = tid; i < 1024; i += 256) {
      int k = i >> 6, n = i & 63;
      float v = 0.f;
      if (k0 + k < ke && bn + n < N) v = B[(size_t)(k0 + k) * ldb + bn + n];
      Bs[k][n] = v;
    }
    __syncthreads();
#pragma unroll
    for (int kk = 0; kk < 16; ++kk) {
      float a[4], b[4];
#pragma unroll
      for (int i = 0; i < 4; i++) a[i] = As[kk][tm + i];
#pragma unroll
      for (int j = 0; j < 4; j++) b[j] = Bs[kk][tn + j];
#pragma unroll
      for (int i = 0; i < 4; i++)
#pragma unroll
        for (int j = 0; j < 4; j++) acc[i][j] += a[i] * b[j];
    }
    __syncthreads();
  }
#pragma unroll
  for (int i = 0; i < 4; i++) {
    int m = bm + tm + i; if (m >= M) continue;
#pragma unroll
    for (int j = 0; j < 4; j++) {
      int n = bn + tn + j; if (n >= N) continue;
      atomicAdd(&C[(size_t)m * ldc + n], acc[i][j]);
    }
  }
}

// ---------------------------------------------------------------------------
// 64x64 f32 tile transpose + bf16 quantize: dst[c][r] = bf16(src[r][c])
// src is R x C (row-major), dst is C x R (row-major). R,C multiples of 64.
// ---------------------------------------------------------------------------
__global__ __launch_bounds__(256) void k_transpose_bf16(
    const float* __restrict__ src, int R, int C,
    unsigned short* __restrict__ dst)
{
  __shared__ float tile[64][65];
  int br = blockIdx.x * 64, bc = blockIdx.y * 64;
  for (int idx = threadIdx.x; idx < 4096; idx += 256) {
    int r = idx >> 6, c = idx & 63;
    tile[r][c] = src[(size_t)(br + r) * C + bc + c];
  }
  __syncthreads();
  for (int idx = threadIdx.x; idx < 4096; idx += 256) {
    int c = idx >> 6, r = idx & 63;
    dst[(size_t)(bc + c) * R + br + r] = f2b(tile[r][c]);
  }
}

// ---------------------------------------------------------------------------
// bf16 MFMA NT GEMM: Cpart[z][M][N] = sum_k At[m][k]*Bt[n][k] over k-chunk z.
// At: M x K bf16 (row-major, K-contiguous), Bt: N x K bf16.
// Tile 64x64, BK=128, 4 waves (each wave: 16-row strip x 64 cols).
// A/B fragments use identical k-mapping k = kk*32 + (lane>>4)*8 + j, so the
// MFMA contraction is correct regardless of the exact HW k-permutation.
// ---------------------------------------------------------------------------
__global__ __launch_bounds__(256) void k_nt_bf16(
    const unsigned short* __restrict__ At,
    const unsigned short* __restrict__ Bt,
    float* __restrict__ Cpart,
    int M, int N, int K, int kchunk)
{
  __shared__ unsigned short Alds[64][136];  // pad 128->136 (272B rows, 16B aligned)
  __shared__ unsigned short Blds[64][136];
  const int bm = blockIdx.x * 64, bn = blockIdx.y * 64;
  const int z = blockIdx.z;
  const int k_beg = z * kchunk, k_end = k_beg + kchunk;
  const int tid = threadIdx.x;
  const int lane = tid & 63, wave = tid >> 6;
  const int lrow = lane & 15, lgrp = lane >> 4;
  f32x4 acc[4];
#pragma unroll
  for (int nt = 0; nt < 4; ++nt) acc[nt] = (f32x4){0.f, 0.f, 0.f, 0.f};

  for (int k0 = k_beg; k0 < k_end; k0 += 128) {
#pragma unroll
    for (int p = 0; p < 4; ++p) {
      int id = p * 256 + tid;   // 0..1023: r = id>>4 (0..63), c = id&15 (16B chunk)
      int r = id >> 4;
      int c = id & 15;
      *(uint4*)(&Alds[r][c * 8]) =
          *(const uint4*)(At + (size_t)(bm + r) * K + k0 + c * 8);
      *(uint4*)(&Blds[r][c * 8]) =
          *(const uint4*)(Bt + (size_t)(bn + r) * K + k0 + c * 8);
    }
    __syncthreads();
#pragma unroll
    for (int kk = 0; kk < 4; ++kk) {
      short8 af = *(const short8*)(&Alds[wave * 16 + lrow][kk * 32 + lgrp * 8]);
#pragma unroll
      for (int nt = 0; nt < 4; ++nt) {
        short8 bf = *(const short8*)(&Blds[nt * 16 + lrow][kk * 32 + lgrp * 8]);
        acc[nt] = __builtin_amdgcn_mfma_f32_16x16x32_bf16(af, bf, acc[nt], 0, 0, 0);
      }
    }
    __syncthreads();
  }
  size_t base = (size_t)z * M * N;
#pragma unroll
  for (int nt = 0; nt < 4; ++nt) {
    int n = bn + nt * 16 + lrow;
#pragma unroll
    for (int r = 0; r < 4; ++r) {
      int m = bm + wave * 16 + lgrp * 4 + r;
      Cpart[base + (size_t)m * N + n] = acc[nt][r];
    }
  }
}

__global__ void k_reduce_parts(const float* __restrict__ part, float* __restrict__ C,
                               int nparts, int sz)
{
  int idx = blockIdx.x * 256 + threadIdx.x;
  if (idx >= sz) return;
  float s = 0.f;
  for (int p = 0; p < nparts; ++p) s += part[(size_t)p * sz + idx];
  C[idx] = s;
}

// ---------------------------------------------------------------------------
// CSR build
// ---------------------------------------------------------------------------
__global__ void k_count(const int* __restrict__ adj, int* __restrict__ counts)
{
  int e = blockIdx.x * 256 + threadIdx.x;
  if (e < EC) atomicAdd(&counts[adj[e]], 1);
}

__global__ __launch_bounds__(1024) void k_scan(const int* __restrict__ counts,
                                               int* __restrict__ offsets)
{
  __shared__ int tsum[1024];
  int tid = threadIdx.x;
  int base = tid * 8;
  int loc[8]; int s = 0;
#pragma unroll
  for (int i = 0; i < 8; i++) { loc[i] = s; s += counts[base + i]; }
  tsum[tid] = s;
  __syncthreads();
  for (int off = 1; off < 1024; off <<= 1) {
    int v = (tid >= off) ? tsum[tid - off] : 0;
    __syncthreads();
    tsum[tid] += v;
    __syncthreads();
  }
  int excl = (tid == 0) ? 0 : tsum[tid - 1];
#pragma unroll
  for (int i = 0; i < 8; i++) offsets[base + i] = excl + loc[i];
  if (tid == 1023) offsets[NC] = tsum[1023];
}

__global__ void k_scatter(const int* __restrict__ adj, const int* __restrict__ offsets,
                          int* __restrict__ fill, int* __restrict__ csr)
{
  int e = blockIdx.x * 256 + threadIdx.x;
  if (e < EC) {
    int d = adj[e], s = adj[EC + e];
    int p = atomicAdd(&fill[d], 1);
    csr[offsets[d] + p] = s;
  }
}

// ---------------------------------------------------------------------------
// Level-0 aggregation (WITH edge multiplicity)
// ---------------------------------------------------------------------------
__global__ __launch_bounds__(256) void k_agg0(
    const int* __restrict__ offsets, const int* __restrict__ csr,
    const float* __restrict__ sPre, const float* __restrict__ t0,
    const float* __restrict__ x,
    float* __restrict__ sAgg, float* __restrict__ z)
{
  int j = blockIdx.x;
  int beg = offsets[j], deg = offsets[j + 1] - beg;
  __shared__ int srcs[1024];
  bool inl = (deg <= 1024);
  if (inl) for (int i = threadIdx.x; i < deg; i += 256) srcs[i] = csr[beg + i];
  __syncthreads();
  for (int c = threadIdx.x; c < P0C; c += 256) {
    float acc = 0.f;
    for (int i = 0; i < deg; i++) {
      int s = inl ? srcs[i] : csr[beg + i];
      acc += sPre[(size_t)s * P0C + c];
    }
    sAgg[(size_t)j * P0C + c] = acc;
  }
  for (int c = threadIdx.x; c < ZIC; c += 256) {
    float acc = 0.f;
    for (int i = 0; i < deg; i++) {
      int s = inl ? srcs[i] : csr[beg + i];
      acc += t0[(size_t)s * ZIC + c];
    }
    z[(size_t)j * DC + 8 + c] = acc;
  }
  if (threadIdx.x < 8) z[(size_t)j * DC + threadIdx.x] = x[(size_t)j * DC + threadIdx.x];
}

// ---------------------------------------------------------------------------
// M = A0_dedup @ S0  (duplicate (dest,src) edges count once)
// ---------------------------------------------------------------------------
__global__ __launch_bounds__(256) void k_aggM(
    const int* __restrict__ offsets, const int* __restrict__ csr,
    const float* __restrict__ S0, float* __restrict__ M)
{
  int j = blockIdx.x;
  int beg = offsets[j], deg = offsets[j + 1] - beg;
  __shared__ int srcs[1024];
  bool inl = (deg <= 1024);
  if (inl) for (int i = threadIdx.x; i < deg; i += 256) srcs[i] = csr[beg + i];
  __syncthreads();
  if (inl) {
    for (int t = threadIdx.x; t < deg; t += 256) {
      int v = srcs[t];
      for (int u = 0; u < t; ++u)
        if (csr[beg + u] == v) { srcs[t] = -1; break; }
    }
  }
  __syncthreads();
  for (int c = threadIdx.x; c < P0C; c += 256) {
    float acc = 0.f;
    for (int i = 0; i < deg; i++) {
      int s = inl ? srcs[i] : csr[beg + i];
      if (!inl) {
        bool dup = false;
        for (int u = 0; u < i; u++) if (csr[beg + u] == s) { dup = true; break; }
        if (dup) s = -1;
      }
      if (s >= 0) acc += S0[(size_t)s * P0C + c];
    }
    M[(size_t)j * P0C + c] = acc;
  }
}

// ---------------------------------------------------------------------------
// Fused expmap0/logmap0 row scale
// ---------------------------------------------------------------------------
__global__ __launch_bounds__(256) void k_rowscale(const float* __restrict__ U, int cols,
                                                  float* __restrict__ rs)
{
  int r = blockIdx.x;
  const float* row = U + (size_t)r * cols;
  float ss = 0.f;
  for (int c = threadIdx.x; c < cols; c += 256) { float v = row[c]; ss += v * v; }
  for (int off = 32; off > 0; off >>= 1) ss += __shfl_down(ss, off);
  __shared__ float red[4];
  if ((threadIdx.x & 63) == 0) red[threadIdx.x >> 6] = ss;
  __syncthreads();
  if (threadIdx.x == 0) {
    float n = sqrtf(red[0] + red[1] + red[2] + red[3]);
    n = fmaxf(n, 1e-15f);
    rs[r] = TEMPC * fminf(n, ATANH_MAX) / n;
  }
}

// ---------------------------------------------------------------------------
// Column softmax (axis=0), two-stage online
// ---------------------------------------------------------------------------
__global__ __launch_bounds__(256) void k_smaxA(const float* __restrict__ U,
    const float* __restrict__ rs, float* __restrict__ pm, float* __restrict__ ps,
    int rows, int cols, int rpg)
{
  int lc = threadIdx.x & 63;
  int c = blockIdx.x * 64 + lc;
  int rl = threadIdx.x >> 6;
  int r0 = blockIdx.y * rpg, r1 = min(rows, r0 + rpg);
  float m = -1e30f, s = 0.f;
  for (int r = r0 + rl; r < r1; r += 4) {
    float l = rs[r] * U[(size_t)r * cols + c];
    if (l > m) { s = s * __expf(m - l) + 1.f; m = l; }
    else s += __expf(l - m);
  }
  __shared__ float sm[4][64], sv[4][64];
  sm[rl][lc] = m; sv[rl][lc] = s;
  __syncthreads();
  if (threadIdx.x < 64) {
    float mm = sm[0][threadIdx.x], s2 = sv[0][threadIdx.x];
    for (int q = 1; q < 4; q++) {
      float mq = sm[q][threadIdx.x], sq = sv[q][threadIdx.x];
      float mn = fmaxf(mm, mq);
      s2 = s2 * __expf(mm - mn) + sq * __expf(mq - mn);
      mm = mn;
    }
    pm[(size_t)blockIdx.y * cols + blockIdx.x * 64 + threadIdx.x] = mm;
    ps[(size_t)blockIdx.y * cols + blockIdx.x * 64 + threadIdx.x] = s2;
  }
}

__global__ void k_smaxB(const float* __restrict__ pm, const float* __restrict__ ps,
                        float* __restrict__ colm, float* __restrict__ colsum,
                        int ng, int cols)
{
  int c = blockIdx.x * blockDim.x + threadIdx.x;
  if (c >= cols) return;
  float m = -1e30f, s = 0.f;
  for (int g = 0; g < ng; g++) {
    float mg = pm[(size_t)g * cols + c], sg = ps[(size_t)g * cols + c];
    float mn = fmaxf(m, mg);
    s = s * __expf(m - mn) + sg * __expf(mg - mn);
    m = mn;
  }
  colm[c] = m; colsum[c] = s;
}

__global__ __launch_bounds__(256) void k_smaxC(const float* __restrict__ U,
    const float* __restrict__ rs, const float* __restrict__ colm,
    const float* __restrict__ colsum, float* __restrict__ S,
    float* __restrict__ loss, int rows, int cols, int rpg)
{
  int lc = threadIdx.x & 63;
  int c = blockIdx.x * 64 + lc;
  int rl = threadIdx.x >> 6;
  int r0 = blockIdx.y * rpg, r1 = min(rows, r0 + rpg);
  float m = colm[c], inv = 1.f / colsum[c];
  float h = 0.f;
  for (int r = r0 + rl; r < r1; r += 4) {
    float l = rs[r] * U[(size_t)r * cols + c];
    float p = __expf(l - m) * inv;
    S[(size_t)r * cols + c] = p;
    if (p > 0.f) h -= p * __logf(p);
  }
  for (int off = 32; off > 0; off >>= 1) h += __shfl_down(h, off);
  __shared__ float red[4];
  if ((threadIdx.x & 63) == 0) red[threadIdx.x >> 6] = h;
  __syncthreads();
  if (threadIdx.x == 0) atomicAdd(loss, red[0] + red[1] + red[2] + red[3]);
}

// single-stage small column softmax (level 1: 512 rows)
__global__ __launch_bounds__(256) void k_smax_small(const float* __restrict__ U,
    const float* __restrict__ rs, float* __restrict__ S, float* __restrict__ loss,
    int rows, int cols)
{
  int lc = threadIdx.x & 63;
  int c = blockIdx.x * 64 + lc;
  int rl = threadIdx.x >> 6;
  float m = -1e30f, s = 0.f;
  for (int r = rl; r < rows; r += 4) {
    float l = rs[r] * U[(size_t)r * cols + c];
    if (l > m) { s = s * __expf(m - l) + 1.f; m = l; }
    else s += __expf(l - m);
  }
  __shared__ float sm[4][64], sv[4][64], fm[64], fs[64];
  sm[rl][lc] = m; sv[rl][lc] = s;
  __syncthreads();
  if (threadIdx.x < 64) {
    float mm = sm[0][threadIdx.x], s2 = sv[0][threadIdx.x];
    for (int q = 1; q < 4; q++) {
      float mq = sm[q][threadIdx.x], sq = sv[q][threadIdx.x];
      float mn = fmaxf(mm, mq);
      s2 = s2 * __expf(mm - mn) + sq * __expf(mq - mn);
      mm = mn;
    }
    fm[threadIdx.x] = mm; fs[threadIdx.x] = s2;
  }
  __syncthreads();
  float M0 = fm[lc], inv = 1.f / fs[lc];
  float h = 0.f;
  for (int r = rl; r < rows; r += 4) {
    float l = rs[r] * U[(size_t)r * cols + c];
    float p = __expf(l - M0) * inv;
    S[(size_t)r * cols + c] = p;
    if (p > 0.f) h -= p * __logf(p);
  }
  for (int off = 32; off > 0; off >>= 1) h += __shfl_down(h, off);
  if ((threadIdx.x & 63) == 0) atomicAdd(loss, h);
}

// ---------------------------------------------------------------------------
// y-projections: out[t,c] += sum_k Y[t,k] * S[k,c]   (T=8 fixed)
// ---------------------------------------------------------------------------
__global__ __launch_bounds__(256) void k_yS(const float* __restrict__ Y, int ldy,
    const float* __restrict__ S, int ldS, float* __restrict__ outp, int ldo,
    int K, int C, int kchunk)
{
  int c = blockIdx.x * 256 + threadIdx.x;
  if (c >= C) return;
  int k0 = blockIdx.y * kchunk, k1 = min(K, k0 + kchunk);
  float acc[8] = {};
  for (int k = k0; k < k1; ++k) {
    float sv = S[(size_t)k * ldS + c];
#pragma unroll
    for (int t = 0; t < 8; t++) acc[t] += Y[(size_t)t * ldy + k] * sv;
  }
#pragma unroll
  for (int t = 0; t < 8; t++) atomicAdd(&outp[(size_t)t * ldo + c], acc[t]);
}

__global__ void k_zbuild1(const float* __restrict__ x1f, const float* __restrict__ zi1,
                          float* __restrict__ z1)
{
  int idx = blockIdx.x * 256 + threadIdx.x;
  if (idx >= P0C * DC) return;
  int r = idx >> 7, c = idx & 127;
  z1[idx] = (c < 8) ? x1f[idx] : zi1[r * ZIC + c - 8];
}

// f32 -> f32 copy/emit with independent src/dst leading dims
__global__ void k_emit(const float* __restrict__ src, int lsrc,
                       float* __restrict__ dst, int ldd, int rows, int cols)
{
  int idx = blockIdx.x * 256 + threadIdx.x;
  if (idx >= rows * cols) return;
  int r = idx / cols, c = idx - r * cols;
  dst[(size_t)r * ldd + c] = src[(size_t)r * lsrc + c];
}

// ---------------------------------------------------------------------------
extern "C" void kernel_launch(void* const* d_in, const int* in_sizes, int n_in,
                              void* d_out, int out_size, void* d_ws, size_t ws_size,
                              hipStream_t stream)
{
  (void)in_sizes; (void)n_in; (void)out_size; (void)ws_size;
  const float* x   = (const float*)d_in[0];
  const float* y   = (const float*)d_in[1];
  const float* We0 = (const float*)d_in[2];
  const float* be0 = (const float*)d_in[3];
  const float* Ws0 = (const float*)d_in[4];
  const float* bs0 = (const float*)d_in[5];
  const float* We1 = (const float*)d_in[6];
  const float* be1 = (const float*)d_in[7];
  const float* Ws1 = (const float*)d_in[8];
  const float* bs1 = (const float*)d_in[9];
  const int*   adj = (const int*)d_in[10];
  float* out = (float*)d_out;

  float* ws = (float*)d_ws;
  size_t o = 0;
  auto alloc = [&](size_t n) { float* p = ws + o; o += n; return p; };
  float* t0    = alloc((size_t)NC * ZIC);
  float* sPre  = alloc((size_t)NC * P0C);   // reused as S0 after softmax
  float* sAgg  = alloc((size_t)NC * P0C);   // reused as Mb, then as A1 partials
  float* zbuf  = alloc((size_t)NC * DC);    // reused as x1 partials
  float* rsc   = alloc(NC);
  float* pm    = alloc(32 * P0C);
  float* ps    = alloc(32 * P0C);
  float* colm  = alloc(P0C);
  float* colsum= alloc(P0C);
  float* t1    = alloc((size_t)P0C * ZIC);
  float* s1pre = alloc((size_t)P0C * P1C);
  float* zi1   = alloc((size_t)P0C * ZIC);
  float* s1agg = alloc((size_t)P0C * P1C);
  float* S1    = alloc((size_t)P0C * P1C);
  float* z1    = alloc((size_t)P0C * P1C);
  float* rs1   = alloc(P0C);
  float* x1f   = alloc((size_t)P0C * DC);      // written by reduce (no memset)
  float* A1    = alloc((size_t)P0C * P0C);     // written by reduce (no memset)
  unsigned short* S0T   = (unsigned short*)alloc((size_t)P0C * NC / 2); // 512x8192 bf16
  unsigned short* MbT   = (unsigned short*)alloc((size_t)P0C * NC / 2); // 512x8192 bf16
  unsigned short* zbufT = (unsigned short*)alloc((size_t)DC * NC / 2);  // 128x8192 bf16
  // atomic-accumulated zone (contiguous, zeroed every call)
  float* x2f   = alloc((size_t)P1C * DC);
  float* y1f   = alloc((size_t)TC * P0C);
  float* y2f   = alloc((size_t)TC * P1C);
  float* lossf = alloc(1);
  size_t atomicFloats = (size_t)P1C*DC + (size_t)TC*P0C + (size_t)TC*P1C + 1;
  o = (o + 63) & ~(size_t)63;
  int* ibase   = (int*)(ws + o);
  int* counts  = ibase;
  int* fill    = ibase + NC;
  int* offsets = ibase + 2 * NC;
  int* csr     = ibase + 2 * NC + (NC + 1);

  float* S0 = sPre;        // alias: sPre dead after k_agg0
  float* Mb = sAgg;        // alias: sAgg dead after S0T/smax done
  float* partsA1 = sAgg;   // alias: Mb dead after MbT transpose (8*512*512 <= NC*P0C)
  float* partsX1 = zbuf;   // alias: zbuf dead after zbufT transpose (16*512*128 == NC*DC)

  hipMemsetAsync(x2f, 0, atomicFloats * sizeof(float), stream);
  hipMemsetAsync(counts, 0, 2 * NC * sizeof(int), stream);

  // ---- level 0 transforms ----
  k_gemm_nn<<<dim3(NC/64, (ZIC+63)/64), 256, 0, stream>>>(x + 8, DC, We0, ZIC, be0, t0, ZIC, NC, ZIC, ZIC);
  k_gemm_nn<<<dim3(NC/64, P0C/64), 256, 0, stream>>>(x, DC, Ws0, P0C, bs0, sPre, P0C, NC, P0C, DC);

  // ---- CSR build ----
  k_count  <<<EC/256, 256, 0, stream>>>(adj, counts);
  k_scan   <<<1, 1024, 0, stream>>>(counts, offsets);
  k_scatter<<<EC/256, 256, 0, stream>>>(adj, offsets, fill, csr);

  // ---- aggregation (with multiplicity) + z assembly ----
  k_agg0<<<NC, 256, 0, stream>>>(offsets, csr, sPre, t0, x, sAgg, zbuf);
  k_transpose_bf16<<<dim3(NC/64, DC/64), 256, 0, stream>>>(zbuf, NC, DC, zbufT);

  // ---- fused expmap/logmap + column softmax -> S0, entropy ----
  k_rowscale<<<NC, 256, 0, stream>>>(sAgg, P0C, rsc);
  k_smaxA<<<dim3(P0C/64, 32), 256, 0, stream>>>(sAgg, rsc, pm, ps, NC, P0C, 256);
  k_smaxB<<<P0C/256, 256, 0, stream>>>(pm, ps, colm, colsum, 32, P0C);
  k_smaxC<<<dim3(P0C/64, 32), 256, 0, stream>>>(sAgg, rsc, colm, colsum, S0, lossf, NC, P0C, 256);
  k_transpose_bf16<<<dim3(NC/64, P0C/64), 256, 0, stream>>>(S0, NC, P0C, S0T);

  // ---- M = A0_dedup @ S0 ; transpose ----
  k_aggM<<<NC, 256, 0, stream>>>(offsets, csr, S0, Mb);
  k_transpose_bf16<<<dim3(NC/64, P0C/64), 256, 0, stream>>>(Mb, NC, P0C, MbT);

  // ---- pooled products via bf16 MFMA (split-K partials + reduce) ----
  // A1 = S0^T @ Mb : M=512 N=512 K=8192, Z=8 (kchunk 1024)
  k_nt_bf16<<<dim3(P0C/64, P0C/64, 8), 256, 0, stream>>>(S0T, MbT, partsA1, P0C, P0C, NC, 1024);
  k_reduce_parts<<<(P0C*P0C)/256, 256, 0, stream>>>(partsA1, A1, 8, P0C*P0C);
  // x1 = S0^T @ z : M=512 N=128 K=8192, Z=16 (kchunk 512)
  k_nt_bf16<<<dim3(P0C/64, DC/64, 16), 256, 0, stream>>>(S0T, zbufT, partsX1, P0C, DC, NC, 512);
  k_reduce_parts<<<(P0C*DC)/256, 256, 0, stream>>>(partsX1, x1f, 16, P0C*DC);
  // y1 = S0^T y^T
  k_yS<<<dim3(P0C/256, 16), 256, 0, stream>>>(y, NC, S0, P0C, y1f, P0C, NC, P0C, NC/16);

  // ---- level 1 ----
  k_gemm_nn<<<dim3(P0C/64, (ZIC+63)/64), 256, 0, stream>>>(x1f + 8, DC, We1, ZIC, be1, t1, ZIC, P0C, ZIC, ZIC);
  k_gemm_nn<<<dim3(P0C/64, P1C/64), 256, 0, stream>>>(x1f, DC, Ws1, P1C, bs1, s1pre, P1C, P0C, P1C, DC);
  k_gemm_nn<<<dim3(P0C/64, (ZIC+63)/64), 256, 0, stream>>>(A1, P0C, t1, ZIC, nullptr, zi1, ZIC, P0C, ZIC, P0C);
  k_gemm_nn<<<dim3(P0C/64, P1C/64), 256, 0, stream>>>(A1, P0C, s1pre, P1C, nullptr, s1agg, P1C, P0C, P1C, P0C);
  k_zbuild1<<<(P0C*DC + 255)/256, 256, 0, stream>>>(x1f, zi1, z1);
  k_rowscale<<<P0C, 256, 0, stream>>>(s1agg, P1C, rs1);
  k_smax_small<<<P1C/64, 256, 0, stream>>>(s1agg, rs1, S1, lossf, P0C, P1C);
  k_gemm_tn<<<dim3(P1C/64, DC/64, 4), 256, 0, stream>>>(S1, P1C, z1, DC, x2f, DC, P1C, DC, P0C, 128);
  k_yS<<<dim3(1, 4), 256, 0, stream>>>(y1f, P0C, S1, P1C, y2f, P1C, P0C, P1C, P0C/4);

  // ---- emit outputs (f32) ----
  const size_t yr_off = (size_t)(NC + P0C + P1C) * DC;  // 1130496
  const int YW = NC + P0C + P1C;                        // 8832
  k_emit<<<(NC*DC + 255)/256, 256, 0, stream>>>(x, DC, out, DC, NC, DC);
  k_emit<<<(P0C*DC + 255)/256, 256, 0, stream>>>(x1f, DC, out + (size_t)NC*DC, DC, P0C, DC);
  k_emit<<<(P1C*DC + 255)/256, 256, 0, stream>>>(x2f, DC, out + (size_t)(NC+P0C)*DC, DC, P1C, DC);
  k_emit<<<(TC*NC + 255)/256, 256, 0, stream>>>(y, NC, out + yr_off, YW, TC, NC);
  k_emit<<<(TC*P0C + 255)/256, 256, 0, stream>>>(y1f, P0C, out + yr_off + NC, YW, TC, P0C);
  k_emit<<<(TC*P1C + 255)/256, 256, 0, stream>>>(y2f, P1C, out + yr_off + NC + P0C, YW, TC, P1C);
  k_emit<<<1, 256, 0, stream>>>(lossf, 1, out + yr_off + (size_t)TC*YW, 1, 1, 1);
}

// Round 4
// 706.875 us; speedup vs baseline: 1.5086x; 1.1670x over previous
//
#include <hip/hip_runtime.h>
#include <hip/hip_bf16.h>

// Problem constants
#define NC   8192
#define EC   131072
#define DC   128
#define TC   8
#define P0C  512
#define P1C  128
#define ZIC  120
#define TEMPC 200.0f
// atanh(float32(1 - 1e-5)) = atanh(0.99999004602432251) -- matches JAX's f32 clip
#define ATANH_MAX 6.1053405f

typedef short short8 __attribute__((ext_vector_type(8)));
typedef float f32x4 __attribute__((ext_vector_type(4)));

__device__ inline unsigned short f2b(float f) {  // f32 -> bf16 bits, RNE
  union { float f; unsigned u; } x; x.f = f;
  unsigned r = x.u + 0x7FFFu + ((x.u >> 16) & 1u);
  return (unsigned short)(r >> 16);
}

// ---------------------------------------------------------------------------
// Tiled f32 GEMM:  C[M,N] = A[M,K](lda) @ B[K,N](ldb) + bias  (bias optional)
// ---------------------------------------------------------------------------
__global__ __launch_bounds__(256) void k_gemm_nn(
    const float* __restrict__ A, int lda,
    const float* __restrict__ B, int ldb,
    const float* __restrict__ bias,
    float* __restrict__ C, int ldc,
    int M, int N, int K)
{
  __shared__ float As[16][65];
  __shared__ float Bs[16][65];
  int bm = blockIdx.x * 64, bn = blockIdx.y * 64;
  int tid = threadIdx.x;
  int tm = (tid >> 4) << 2, tn = (tid & 15) << 2;
  float acc[4][4] = {};
  for (int k0 = 0; k0 < K; k0 += 16) {
    for (int i = tid; i < 1024; i += 256) {
      int m = i >> 4, k = i & 15;
      float v = 0.f;
      if (bm + m < M && k0 + k < K) v = A[(size_t)(bm + m) * lda + k0 + k];
      As[k][m] = v;
    }
    for (int i = tid; i < 1024; i += 256) {
      int k = i >> 6, n = i & 63;
      float v = 0.f;
      if (k0 + k < K && bn + n < N) v = B[(size_t)(k0 + k) * ldb + bn + n];
      Bs[k][n] = v;
    }
    __syncthreads();
#pragma unroll
    for (int kk = 0; kk < 16; ++kk) {
      float a[4], b[4];
#pragma unroll
      for (int i = 0; i < 4; i++) a[i] = As[kk][tm + i];
#pragma unroll
      for (int j = 0; j < 4; j++) b[j] = Bs[kk][tn + j];
#pragma unroll
      for (int i = 0; i < 4; i++)
#pragma unroll
        for (int j = 0; j < 4; j++) acc[i][j] += a[i] * b[j];
    }
    __syncthreads();
  }
#pragma unroll
  for (int i = 0; i < 4; i++) {
    int m = bm + tm + i; if (m >= M) continue;
#pragma unroll
    for (int j = 0; j < 4; j++) {
      int n = bn + tn + j; if (n >= N) continue;
      float v = acc[i][j];
      if (bias) v += bias[n];
      C[(size_t)m * ldc + n] = v;
    }
  }
}

// ---------------------------------------------------------------------------
// Small f32 TN GEMM with split-K + atomics (kept for the tiny x2 product)
// ---------------------------------------------------------------------------
__global__ __launch_bounds__(256) void k_gemm_tn(
    const float* __restrict__ A, int lda,
    const float* __restrict__ B, int ldb,
    float* __restrict__ C, int ldc,
    int M, int N, int K, int kchunk)
{
  __shared__ float As[16][65];
  __shared__ float Bs[16][65];
  int bm = blockIdx.x * 64, bn = blockIdx.y * 64;
  int ks = blockIdx.z * kchunk;
  int ke = min(K, ks + kchunk);
  int tid = threadIdx.x;
  int tm = (tid >> 4) << 2, tn = (tid & 15) << 2;
  float acc[4][4] = {};
  for (int k0 = ks; k0 < ke; k0 += 16) {
    for (int i = tid; i < 1024; i += 256) {
      int k = i >> 6, m = i & 63;
      float v = 0.f;
      if (k0 + k < ke && bm + m < M) v = A[(size_t)(k0 + k) * lda + bm + m];
      As[k][m] = v;
    }
    for (int i = tid; i < 1024; i += 256) {
      int k = i >> 6, n = i & 63;
      float v = 0.f;
      if (k0 + k < ke && bn + n < N) v = B[(size_t)(k0 + k) * ldb + bn + n];
      Bs[k][n] = v;
    }
    __syncthreads();
#pragma unroll
    for (int kk = 0; kk < 16; ++kk) {
      float a[4], b[4];
#pragma unroll
      for (int i = 0; i < 4; i++) a[i] = As[kk][tm + i];
#pragma unroll
      for (int j = 0; j < 4; j++) b[j] = Bs[kk][tn + j];
#pragma unroll
      for (int i = 0; i < 4; i++)
#pragma unroll
        for (int j = 0; j < 4; j++) acc[i][j] += a[i] * b[j];
    }
    __syncthreads();
  }
#pragma unroll
  for (int i = 0; i < 4; i++) {
    int m = bm + tm + i; if (m >= M) continue;
#pragma unroll
    for (int j = 0; j < 4; j++) {
      int n = bn + tn + j; if (n >= N) continue;
      atomicAdd(&C[(size_t)m * ldc + n], acc[i][j]);
    }
  }
}

// ---------------------------------------------------------------------------
// 64x64 f32 tile transpose + bf16 quantize: dst[c][r] = bf16(src[r][c])
// ---------------------------------------------------------------------------
__global__ __launch_bounds__(256) void k_transpose_bf16(
    const float* __restrict__ src, int R, int C,
    unsigned short* __restrict__ dst)
{
  __shared__ float tile[64][65];
  int br = blockIdx.x * 64, bc = blockIdx.y * 64;
  for (int idx = threadIdx.x; idx < 4096; idx += 256) {
    int r = idx >> 6, c = idx & 63;
    tile[r][c] = src[(size_t)(br + r) * C + bc + c];
  }
  __syncthreads();
  for (int idx = threadIdx.x; idx < 4096; idx += 256) {
    int c = idx >> 6, r = idx & 63;
    dst[(size_t)(bc + c) * R + br + r] = f2b(tile[r][c]);
  }
}

// ---------------------------------------------------------------------------
// bf16 MFMA NT GEMM: Cpart[z][M][N] = sum_k At[m][k]*Bt[n][k] over k-chunk z.
// ---------------------------------------------------------------------------
__global__ __launch_bounds__(256) void k_nt_bf16(
    const unsigned short* __restrict__ At,
    const unsigned short* __restrict__ Bt,
    float* __restrict__ Cpart,
    int M, int N, int K, int kchunk)
{
  __shared__ unsigned short Alds[64][136];  // pad 128->136 (272B rows, 16B aligned)
  __shared__ unsigned short Blds[64][136];
  const int bm = blockIdx.x * 64, bn = blockIdx.y * 64;
  const int z = blockIdx.z;
  const int k_beg = z * kchunk, k_end = k_beg + kchunk;
  const int tid = threadIdx.x;
  const int lane = tid & 63, wave = tid >> 6;
  const int lrow = lane & 15, lgrp = lane >> 4;
  f32x4 acc[4];
#pragma unroll
  for (int nt = 0; nt < 4; ++nt) acc[nt] = (f32x4){0.f, 0.f, 0.f, 0.f};

  for (int k0 = k_beg; k0 < k_end; k0 += 128) {
#pragma unroll
    for (int p = 0; p < 4; ++p) {
      int id = p * 256 + tid;
      int r = id >> 4;
      int c = id & 15;
      *(uint4*)(&Alds[r][c * 8]) =
          *(const uint4*)(At + (size_t)(bm + r) * K + k0 + c * 8);
      *(uint4*)(&Blds[r][c * 8]) =
          *(const uint4*)(Bt + (size_t)(bn + r) * K + k0 + c * 8);
    }
    __syncthreads();
#pragma unroll
    for (int kk = 0; kk < 4; ++kk) {
      short8 af = *(const short8*)(&Alds[wave * 16 + lrow][kk * 32 + lgrp * 8]);
#pragma unroll
      for (int nt = 0; nt < 4; ++nt) {
        short8 bf = *(const short8*)(&Blds[nt * 16 + lrow][kk * 32 + lgrp * 8]);
        acc[nt] = __builtin_amdgcn_mfma_f32_16x16x32_bf16(af, bf, acc[nt], 0, 0, 0);
      }
    }
    __syncthreads();
  }
  size_t base = (size_t)z * M * N;
#pragma unroll
  for (int nt = 0; nt < 4; ++nt) {
    int n = bn + nt * 16 + lrow;
#pragma unroll
    for (int r = 0; r < 4; ++r) {
      int m = bm + wave * 16 + lgrp * 4 + r;
      Cpart[base + (size_t)m * N + n] = acc[nt][r];
    }
  }
}

__global__ void k_reduce_parts(const float* __restrict__ part, float* __restrict__ C,
                               int nparts, int sz)
{
  int idx = blockIdx.x * 256 + threadIdx.x;
  if (idx >= sz) return;
  float s = 0.f;
  for (int p = 0; p < nparts; ++p) s += part[(size_t)p * sz + idx];
  C[idx] = s;
}

// ---------------------------------------------------------------------------
// CSR build
// ---------------------------------------------------------------------------
__global__ void k_count(const int* __restrict__ adj, int* __restrict__ counts)
{
  int e = blockIdx.x * 256 + threadIdx.x;
  if (e < EC) atomicAdd(&counts[adj[e]], 1);
}

__global__ __launch_bounds__(1024) void k_scan(const int* __restrict__ counts,
                                               int* __restrict__ offsets)
{
  __shared__ int tsum[1024];
  int tid = threadIdx.x;
  int base = tid * 8;
  int loc[8]; int s = 0;
#pragma unroll
  for (int i = 0; i < 8; i++) { loc[i] = s; s += counts[base + i]; }
  tsum[tid] = s;
  __syncthreads();
  for (int off = 1; off < 1024; off <<= 1) {
    int v = (tid >= off) ? tsum[tid - off] : 0;
    __syncthreads();
    tsum[tid] += v;
    __syncthreads();
  }
  int excl = (tid == 0) ? 0 : tsum[tid - 1];
#pragma unroll
  for (int i = 0; i < 8; i++) offsets[base + i] = excl + loc[i];
  if (tid == 1023) offsets[NC] = tsum[1023];
}

__global__ void k_scatter(const int* __restrict__ adj, const int* __restrict__ offsets,
                          int* __restrict__ fill, int* __restrict__ csr)
{
  int e = blockIdx.x * 256 + threadIdx.x;
  if (e < EC) {
    int d = adj[e], s = adj[EC + e];
    int p = atomicAdd(&fill[d], 1);
    csr[offsets[d] + p] = s;
  }
}

// ---------------------------------------------------------------------------
// Level-0 aggregation (WITH edge multiplicity)
// ---------------------------------------------------------------------------
__global__ __launch_bounds__(256) void k_agg0(
    const int* __restrict__ offsets, const int* __restrict__ csr,
    const float* __restrict__ sPre, const float* __restrict__ t0,
    const float* __restrict__ x,
    float* __restrict__ sAgg, float* __restrict__ z)
{
  int j = blockIdx.x;
  int beg = offsets[j], deg = offsets[j + 1] - beg;
  __shared__ int srcs[1024];
  bool inl = (deg <= 1024);
  if (inl) for (int i = threadIdx.x; i < deg; i += 256) srcs[i] = csr[beg + i];
  __syncthreads();
  for (int c = threadIdx.x; c < P0C; c += 256) {
    float acc = 0.f;
    for (int i = 0; i < deg; i++) {
      int s = inl ? srcs[i] : csr[beg + i];
      acc += sPre[(size_t)s * P0C + c];
    }
    sAgg[(size_t)j * P0C + c] = acc;
  }
  for (int c = threadIdx.x; c < ZIC; c += 256) {
    float acc = 0.f;
    for (int i = 0; i < deg; i++) {
      int s = inl ? srcs[i] : csr[beg + i];
      acc += t0[(size_t)s * ZIC + c];
    }
    z[(size_t)j * DC + 8 + c] = acc;
  }
  if (threadIdx.x < 8) z[(size_t)j * DC + threadIdx.x] = x[(size_t)j * DC + threadIdx.x];
}

// ---------------------------------------------------------------------------
// M = A0_dedup @ S0  (duplicate (dest,src) edges count once)
// ---------------------------------------------------------------------------
__global__ __launch_bounds__(256) void k_aggM(
    const int* __restrict__ offsets, const int* __restrict__ csr,
    const float* __restrict__ S0, float* __restrict__ M)
{
  int j = blockIdx.x;
  int beg = offsets[j], deg = offsets[j + 1] - beg;
  __shared__ int srcs[1024];
  bool inl = (deg <= 1024);
  if (inl) for (int i = threadIdx.x; i < deg; i += 256) srcs[i] = csr[beg + i];
  __syncthreads();
  if (inl) {
    for (int t = threadIdx.x; t < deg; t += 256) {
      int v = srcs[t];
      for (int u = 0; u < t; ++u)
        if (csr[beg + u] == v) { srcs[t] = -1; break; }
    }
  }
  __syncthreads();
  for (int c = threadIdx.x; c < P0C; c += 256) {
    float acc = 0.f;
    for (int i = 0; i < deg; i++) {
      int s = inl ? srcs[i] : csr[beg + i];
      if (!inl) {
        bool dup = false;
        for (int u = 0; u < i; u++) if (csr[beg + u] == s) { dup = true; break; }
        if (dup) s = -1;
      }
      if (s >= 0) acc += S0[(size_t)s * P0C + c];
    }
    M[(size_t)j * P0C + c] = acc;
  }
}

// ---------------------------------------------------------------------------
// Fused expmap0/logmap0 row scale
// ---------------------------------------------------------------------------
__global__ __launch_bounds__(256) void k_rowscale(const float* __restrict__ U, int cols,
                                                  float* __restrict__ rs)
{
  int r = blockIdx.x;
  const float* row = U + (size_t)r * cols;
  float ss = 0.f;
  for (int c = threadIdx.x; c < cols; c += 256) { float v = row[c]; ss += v * v; }
  for (int off = 32; off > 0; off >>= 1) ss += __shfl_down(ss, off);
  __shared__ float red[4];
  if ((threadIdx.x & 63) == 0) red[threadIdx.x >> 6] = ss;
  __syncthreads();
  if (threadIdx.x == 0) {
    float n = sqrtf(red[0] + red[1] + red[2] + red[3]);
    n = fmaxf(n, 1e-15f);
    rs[r] = TEMPC * fminf(n, ATANH_MAX) / n;
  }
}

// ---------------------------------------------------------------------------
// Column softmax (axis=0), two-stage online
// ---------------------------------------------------------------------------
__global__ __launch_bounds__(256) void k_smaxA(const float* __restrict__ U,
    const float* __restrict__ rs, float* __restrict__ pm, float* __restrict__ ps,
    int rows, int cols, int rpg)
{
  int lc = threadIdx.x & 63;
  int c = blockIdx.x * 64 + lc;
  int rl = threadIdx.x >> 6;
  int r0 = blockIdx.y * rpg, r1 = min(rows, r0 + rpg);
  float m = -1e30f, s = 0.f;
  for (int r = r0 + rl; r < r1; r += 4) {
    float l = rs[r] * U[(size_t)r * cols + c];
    if (l > m) { s = s * __expf(m - l) + 1.f; m = l; }
    else s += __expf(l - m);
  }
  __shared__ float sm[4][64], sv[4][64];
  sm[rl][lc] = m; sv[rl][lc] = s;
  __syncthreads();
  if (threadIdx.x < 64) {
    float mm = sm[0][threadIdx.x], s2 = sv[0][threadIdx.x];
    for (int q = 1; q < 4; q++) {
      float mq = sm[q][threadIdx.x], sq = sv[q][threadIdx.x];
      float mn = fmaxf(mm, mq);
      s2 = s2 * __expf(mm - mn) + sq * __expf(mq - mn);
      mm = mn;
    }
    pm[(size_t)blockIdx.y * cols + blockIdx.x * 64 + threadIdx.x] = mm;
    ps[(size_t)blockIdx.y * cols + blockIdx.x * 64 + threadIdx.x] = s2;
  }
}

__global__ void k_smaxB(const float* __restrict__ pm, const float* __restrict__ ps,
                        float* __restrict__ colm, float* __restrict__ colsum,
                        int ng, int cols)
{
  int c = blockIdx.x * blockDim.x + threadIdx.x;
  if (c >= cols) return;
  float m = -1e30f, s = 0.f;
  for (int g = 0; g < ng; g++) {
    float mg = pm[(size_t)g * cols + c], sg = ps[(size_t)g * cols + c];
    float mn = fmaxf(m, mg);
    s = s * __expf(m - mn) + sg * __expf(mg - mn);
    m = mn;
  }
  colm[c] = m; colsum[c] = s;
}

__global__ __launch_bounds__(256) void k_smaxC(const float* __restrict__ U,
    const float* __restrict__ rs, const float* __restrict__ colm,
    const float* __restrict__ colsum, float* __restrict__ S,
    float* __restrict__ loss, int rows, int cols, int rpg)
{
  int lc = threadIdx.x & 63;
  int c = blockIdx.x * 64 + lc;
  int rl = threadIdx.x >> 6;
  int r0 = blockIdx.y * rpg, r1 = min(rows, r0 + rpg);
  float m = colm[c], inv = 1.f / colsum[c];
  float h = 0.f;
  for (int r = r0 + rl; r < r1; r += 4) {
    float l = rs[r] * U[(size_t)r * cols + c];
    float p = __expf(l - m) * inv;
    S[(size_t)r * cols + c] = p;
    if (p > 0.f) h -= p * __logf(p);
  }
  for (int off = 32; off > 0; off >>= 1) h += __shfl_down(h, off);
  __shared__ float red[4];
  if ((threadIdx.x & 63) == 0) red[threadIdx.x >> 6] = h;
  __syncthreads();
  if (threadIdx.x == 0) atomicAdd(loss, red[0] + red[1] + red[2] + red[3]);
}

// single-stage small column softmax (level 1: 512 rows)
__global__ __launch_bounds__(256) void k_smax_small(const float* __restrict__ U,
    const float* __restrict__ rs, float* __restrict__ S, float* __restrict__ loss,
    int rows, int cols)
{
  int lc = threadIdx.x & 63;
  int c = blockIdx.x * 64 + lc;
  int rl = threadIdx.x >> 6;
  float m = -1e30f, s = 0.f;
  for (int r = rl; r < rows; r += 4) {
    float l = rs[r] * U[(size_t)r * cols + c];
    if (l > m) { s = s * __expf(m - l) + 1.f; m = l; }
    else s += __expf(l - m);
  }
  __shared__ float sm[4][64], sv[4][64], fm[64], fs[64];
  sm[rl][lc] = m; sv[rl][lc] = s;
  __syncthreads();
  if (threadIdx.x < 64) {
    float mm = sm[0][threadIdx.x], s2 = sv[0][threadIdx.x];
    for (int q = 1; q < 4; q++) {
      float mq = sm[q][threadIdx.x], sq = sv[q][threadIdx.x];
      float mn = fmaxf(mm, mq);
      s2 = s2 * __expf(mm - mn) + sq * __expf(mq - mn);
      mm = mn;
    }
    fm[threadIdx.x] = mm; fs[threadIdx.x] = s2;
  }
  __syncthreads();
  float M0 = fm[lc], inv = 1.f / fs[lc];
  float h = 0.f;
  for (int r = rl; r < rows; r += 4) {
    float l = rs[r] * U[(size_t)r * cols + c];
    float p = __expf(l - M0) * inv;
    S[(size_t)r * cols + c] = p;
    if (p > 0.f) h -= p * __logf(p);
  }
  for (int off = 32; off > 0; off >>= 1) h += __shfl_down(h, off);
  if ((threadIdx.x & 63) == 0) atomicAdd(loss, h);
}

// ---------------------------------------------------------------------------
// y-projection via split-K partials: part[kb][t][C] = sum_{k in chunk} Y[t,k]*S[k,c]
// grid (C/64, KB), block 256 (4 row-lanes x 64 cols). Y reads are wave-uniform.
// ---------------------------------------------------------------------------
__global__ __launch_bounds__(256) void k_yS_part(
    const float* __restrict__ Y, int ldy,
    const float* __restrict__ S, int ldS,
    float* __restrict__ part, int K, int C, int kchunk)
{
  int lc = threadIdx.x & 63;
  int c = blockIdx.x * 64 + lc;
  int rl = threadIdx.x >> 6;
  int r0 = blockIdx.y * kchunk, r1 = min(K, r0 + kchunk);
  float acc[8] = {};
  for (int r = r0 + rl; r < r1; r += 4) {
    float sv = S[(size_t)r * ldS + c];
#pragma unroll
    for (int t = 0; t < 8; t++) acc[t] += Y[(size_t)t * ldy + r] * sv;
  }
  __shared__ float red[4][8][64];
#pragma unroll
  for (int t = 0; t < 8; t++) red[rl][t][lc] = acc[t];
  __syncthreads();
  if (rl == 0) {
#pragma unroll
    for (int t = 0; t < 8; t++) {
      float v = red[0][t][lc] + red[1][t][lc] + red[2][t][lc] + red[3][t][lc];
      part[((size_t)blockIdx.y * 8 + t) * C + c] = v;
    }
  }
}

__global__ void k_yS_red(const float* __restrict__ part, float* __restrict__ outp,
                         int nparts, int sz)
{
  int idx = blockIdx.x * 256 + threadIdx.x;
  if (idx >= sz) return;
  float s = 0.f;
  for (int p = 0; p < nparts; ++p) s += part[(size_t)p * sz + idx];
  outp[idx] = s;
}

__global__ void k_zbuild1(const float* __restrict__ x1f, const float* __restrict__ zi1,
                          float* __restrict__ z1)
{
  int idx = blockIdx.x * 256 + threadIdx.x;
  if (idx >= P0C * DC) return;
  int r = idx >> 7, c = idx & 127;
  z1[idx] = (c < 8) ? x1f[idx] : zi1[r * ZIC + c - 8];
}

// f32 -> f32 copy/emit with independent src/dst leading dims
__global__ void k_emit(const float* __restrict__ src, int lsrc,
                       float* __restrict__ dst, int ldd, int rows, int cols)
{
  int idx = blockIdx.x * 256 + threadIdx.x;
  if (idx >= rows * cols) return;
  int r = idx / cols, c = idx - r * cols;
  dst[(size_t)r * ldd + c] = src[(size_t)r * lsrc + c];
}

// ---------------------------------------------------------------------------
extern "C" void kernel_launch(void* const* d_in, const int* in_sizes, int n_in,
                              void* d_out, int out_size, void* d_ws, size_t ws_size,
                              hipStream_t stream)
{
  (void)in_sizes; (void)n_in; (void)out_size; (void)ws_size;
  const float* x   = (const float*)d_in[0];
  const float* y   = (const float*)d_in[1];
  const float* We0 = (const float*)d_in[2];
  const float* be0 = (const float*)d_in[3];
  const float* Ws0 = (const float*)d_in[4];
  const float* bs0 = (const float*)d_in[5];
  const float* We1 = (const float*)d_in[6];
  const float* be1 = (const float*)d_in[7];
  const float* Ws1 = (const float*)d_in[8];
  const float* bs1 = (const float*)d_in[9];
  const int*   adj = (const int*)d_in[10];
  float* out = (float*)d_out;

  float* ws = (float*)d_ws;
  size_t o = 0;
  auto alloc = [&](size_t n) { float* p = ws + o; o += n; return p; };
  float* t0    = alloc((size_t)NC * ZIC);
  float* sPre  = alloc((size_t)NC * P0C);   // reused as S0 after softmax
  float* sAgg  = alloc((size_t)NC * P0C);   // reused as Mb, then as A1 partials
  float* zbuf  = alloc((size_t)NC * DC);    // reused as x1 partials
  float* rsc   = alloc(NC);
  float* pm    = alloc(32 * P0C);
  float* ps    = alloc(32 * P0C);
  float* colm  = alloc(P0C);
  float* colsum= alloc(P0C);
  float* t1    = alloc((size_t)P0C * ZIC);
  float* s1pre = alloc((size_t)P0C * P1C);
  float* zi1   = alloc((size_t)P0C * ZIC);
  float* s1agg = alloc((size_t)P0C * P1C);
  float* S1    = alloc((size_t)P0C * P1C);
  float* z1    = alloc((size_t)P0C * P1C);
  float* rs1   = alloc(P0C);
  float* x1f   = alloc((size_t)P0C * DC);      // written by reduce (no memset)
  float* A1    = alloc((size_t)P0C * P0C);     // written by reduce (no memset)
  unsigned short* S0T   = (unsigned short*)alloc((size_t)P0C * NC / 2); // 512x8192 bf16
  unsigned short* MbT   = (unsigned short*)alloc((size_t)P0C * NC / 2); // 512x8192 bf16
  unsigned short* zbufT = (unsigned short*)alloc((size_t)DC * NC / 2);  // 128x8192 bf16
  float* partY1 = alloc((size_t)128 * TC * P0C);  // 128 chunks x 8 x 512
  float* partY2 = alloc((size_t)8 * TC * P1C);    // 8 chunks x 8 x 128
  // atomic-accumulated zone (contiguous, zeroed every call)
  float* x2f   = alloc((size_t)P1C * DC);
  float* y1f   = alloc((size_t)TC * P0C);
  float* y2f   = alloc((size_t)TC * P1C);
  float* lossf = alloc(1);
  size_t atomicFloats = (size_t)P1C*DC + (size_t)TC*P0C + (size_t)TC*P1C + 1;
  o = (o + 63) & ~(size_t)63;
  int* ibase   = (int*)(ws + o);
  int* counts  = ibase;
  int* fill    = ibase + NC;
  int* offsets = ibase + 2 * NC;
  int* csr     = ibase + 2 * NC + (NC + 1);

  float* S0 = sPre;        // alias: sPre dead after k_agg0
  float* Mb = sAgg;        // alias: sAgg dead after S0T/smax done
  float* partsA1 = sAgg;   // alias: Mb dead after MbT transpose (8*512*512 <= NC*P0C)
  float* partsX1 = zbuf;   // alias: zbuf dead after zbufT transpose (16*512*128 == NC*DC)

  hipMemsetAsync(x2f, 0, atomicFloats * sizeof(float), stream);
  hipMemsetAsync(counts, 0, 2 * NC * sizeof(int), stream);

  // ---- level 0 transforms ----
  k_gemm_nn<<<dim3(NC/64, (ZIC+63)/64), 256, 0, stream>>>(x + 8, DC, We0, ZIC, be0, t0, ZIC, NC, ZIC, ZIC);
  k_gemm_nn<<<dim3(NC/64, P0C/64), 256, 0, stream>>>(x, DC, Ws0, P0C, bs0, sPre, P0C, NC, P0C, DC);

  // ---- CSR build ----
  k_count  <<<EC/256, 256, 0, stream>>>(adj, counts);
  k_scan   <<<1, 1024, 0, stream>>>(counts, offsets);
  k_scatter<<<EC/256, 256, 0, stream>>>(adj, offsets, fill, csr);

  // ---- aggregation (with multiplicity) + z assembly ----
  k_agg0<<<NC, 256, 0, stream>>>(offsets, csr, sPre, t0, x, sAgg, zbuf);
  k_transpose_bf16<<<dim3(NC/64, DC/64), 256, 0, stream>>>(zbuf, NC, DC, zbufT);

  // ---- fused expmap/logmap + column softmax -> S0, entropy ----
  k_rowscale<<<NC, 256, 0, stream>>>(sAgg, P0C, rsc);
  k_smaxA<<<dim3(P0C/64, 32), 256, 0, stream>>>(sAgg, rsc, pm, ps, NC, P0C, 256);
  k_smaxB<<<P0C/256, 256, 0, stream>>>(pm, ps, colm, colsum, 32, P0C);
  k_smaxC<<<dim3(P0C/64, 32), 256, 0, stream>>>(sAgg, rsc, colm, colsum, S0, lossf, NC, P0C, 256);
  k_transpose_bf16<<<dim3(NC/64, P0C/64), 256, 0, stream>>>(S0, NC, P0C, S0T);

  // ---- M = A0_dedup @ S0 ; transpose ----
  k_aggM<<<NC, 256, 0, stream>>>(offsets, csr, S0, Mb);
  k_transpose_bf16<<<dim3(NC/64, P0C/64), 256, 0, stream>>>(Mb, NC, P0C, MbT);

  // ---- pooled products via bf16 MFMA (split-K partials + reduce) ----
  // A1 = S0^T @ Mb : M=512 N=512 K=8192, Z=8 (kchunk 1024)
  k_nt_bf16<<<dim3(P0C/64, P0C/64, 8), 256, 0, stream>>>(S0T, MbT, partsA1, P0C, P0C, NC, 1024);
  k_reduce_parts<<<(P0C*P0C)/256, 256, 0, stream>>>(partsA1, A1, 8, P0C*P0C);
  // x1 = S0^T @ z : M=512 N=128 K=8192, Z=16 (kchunk 512)
  k_nt_bf16<<<dim3(P0C/64, DC/64, 16), 256, 0, stream>>>(S0T, zbufT, partsX1, P0C, DC, NC, 512);
  k_reduce_parts<<<(P0C*DC)/256, 256, 0, stream>>>(partsX1, x1f, 16, P0C*DC);
  // y1 = y @ S0 : split-K partials (128 chunks of 64 rows) + reduce
  k_yS_part<<<dim3(P0C/64, 128), 256, 0, stream>>>(y, NC, S0, P0C, partY1, NC, P0C, 64);
  k_yS_red<<<(TC*P0C + 255)/256, 256, 0, stream>>>(partY1, y1f, 128, TC*P0C);

  // ---- level 1 ----
  k_gemm_nn<<<dim3(P0C/64, (ZIC+63)/64), 256, 0, stream>>>(x1f + 8, DC, We1, ZIC, be1, t1, ZIC, P0C, ZIC, ZIC);
  k_gemm_nn<<<dim3(P0C/64, P1C/64), 256, 0, stream>>>(x1f, DC, Ws1, P1C, bs1, s1pre, P1C, P0C, P1C, DC);
  k_gemm_nn<<<dim3(P0C/64, (ZIC+63)/64), 256, 0, stream>>>(A1, P0C, t1, ZIC, nullptr, zi1, ZIC, P0C, ZIC, P0C);
  k_gemm_nn<<<dim3(P0C/64, P1C/64), 256, 0, stream>>>(A1, P0C, s1pre, P1C, nullptr, s1agg, P1C, P0C, P1C, P0C);
  k_zbuild1<<<(P0C*DC + 255)/256, 256, 0, stream>>>(x1f, zi1, z1);
  k_rowscale<<<P0C, 256, 0, stream>>>(s1agg, P1C, rs1);
  k_smax_small<<<P1C/64, 256, 0, stream>>>(s1agg, rs1, S1, lossf, P0C, P1C);
  k_gemm_tn<<<dim3(P1C/64, DC/64, 4), 256, 0, stream>>>(S1, P1C, z1, DC, x2f, DC, P1C, DC, P0C, 128);
  // y2 = y1 @ S1 : split-K partials (8 chunks of 64 rows) + reduce
  k_yS_part<<<dim3(P1C/64, 8), 256, 0, stream>>>(y1f, P0C, S1, P1C, partY2, P0C, P1C, 64);
  k_yS_red<<<(TC*P1C + 255)/256, 256, 0, stream>>>(partY2, y2f, 8, TC*P1C);

  // ---- emit outputs (f32) ----
  const size_t yr_off = (size_t)(NC + P0C + P1C) * DC;  // 1130496
  const int YW = NC + P0C + P1C;                        // 8832
  k_emit<<<(NC*DC + 255)/256, 256, 0, stream>>>(x, DC, out, DC, NC, DC);
  k_emit<<<(P0C*DC + 255)/256, 256, 0, stream>>>(x1f, DC, out + (size_t)NC*DC, DC, P0C, DC);
  k_emit<<<(P1C*DC + 255)/256, 256, 0, stream>>>(x2f, DC, out + (size_t)(NC+P0C)*DC, DC, P1C, DC);
  k_emit<<<(TC*NC + 255)/256, 256, 0, stream>>>(y, NC, out + yr_off, YW, TC, NC);
  k_emit<<<(TC*P0C + 255)/256, 256, 0, stream>>>(y1f, P0C, out + yr_off + NC, YW, TC, P0C);
  k_emit<<<(TC*P1C + 255)/256, 256, 0, stream>>>(y2f, P1C, out + yr_off + NC + P0C, YW, TC, P1C);
  k_emit<<<1, 256, 0, stream>>>(lossf, 1, out + yr_off + (size_t)TC*YW, 1, 1, 1);
}

// Round 5
// 555.034 us; speedup vs baseline: 1.9214x; 1.2736x over previous
//
#include <hip/hip_runtime.h>
#include <hip/hip_bf16.h>

// Problem constants
#define NC   8192
#define EC   131072
#define DC   128
#define TC   8
#define P0C  512
#define P1C  128
#define ZIC  120
#define TEMPC 200.0f
// atanh(float32(1 - 1e-5)) = atanh(0.99999004602432251) -- matches JAX's f32 clip
#define ATANH_MAX 6.1053405f

typedef short short8 __attribute__((ext_vector_type(8)));
typedef float f32x4 __attribute__((ext_vector_type(4)));

__device__ inline unsigned short f2b(float f) {  // f32 -> bf16 bits, RNE
  union { float f; unsigned u; } x; x.f = f;
  unsigned r = x.u + 0x7FFFu + ((x.u >> 16) & 1u);
  return (unsigned short)(r >> 16);
}

// ---------------------------------------------------------------------------
// Tiled f32 GEMM:  C[M,N] = A[M,K](lda) @ B[K,N](ldb) + bias  (bias optional)
// ---------------------------------------------------------------------------
__global__ __launch_bounds__(256) void k_gemm_nn(
    const float* __restrict__ A, int lda,
    const float* __restrict__ B, int ldb,
    const float* __restrict__ bias,
    float* __restrict__ C, int ldc,
    int M, int N, int K)
{
  __shared__ float As[16][65];
  __shared__ float Bs[16][65];
  int bm = blockIdx.x * 64, bn = blockIdx.y * 64;
  int tid = threadIdx.x;
  int tm = (tid >> 4) << 2, tn = (tid & 15) << 2;
  float acc[4][4] = {};
  for (int k0 = 0; k0 < K; k0 += 16) {
    for (int i = tid; i < 1024; i += 256) {
      int m = i >> 4, k = i & 15;
      float v = 0.f;
      if (bm + m < M && k0 + k < K) v = A[(size_t)(bm + m) * lda + k0 + k];
      As[k][m] = v;
    }
    for (int i = tid; i < 1024; i += 256) {
      int k = i >> 6, n = i & 63;
      float v = 0.f;
      if (k0 + k < K && bn + n < N) v = B[(size_t)(k0 + k) * ldb + bn + n];
      Bs[k][n] = v;
    }
    __syncthreads();
#pragma unroll
    for (int kk = 0; kk < 16; ++kk) {
      float a[4], b[4];
#pragma unroll
      for (int i = 0; i < 4; i++) a[i] = As[kk][tm + i];
#pragma unroll
      for (int j = 0; j < 4; j++) b[j] = Bs[kk][tn + j];
#pragma unroll
      for (int i = 0; i < 4; i++)
#pragma unroll
        for (int j = 0; j < 4; j++) acc[i][j] += a[i] * b[j];
    }
    __syncthreads();
  }
#pragma unroll
  for (int i = 0; i < 4; i++) {
    int m = bm + tm + i; if (m >= M) continue;
#pragma unroll
    for (int j = 0; j < 4; j++) {
      int n = bn + tn + j; if (n >= N) continue;
      float v = acc[i][j];
      if (bias) v += bias[n];
      C[(size_t)m * ldc + n] = v;
    }
  }
}

// ---------------------------------------------------------------------------
// f32 NN GEMM, split-K partials: part[z][M][N] = A[M, kchunk] @ B[kchunk, N]
// grid (M/64, ceil(N/64), KB). Exact f32 (no atomics); reduce adds bias.
// ---------------------------------------------------------------------------
__global__ __launch_bounds__(256) void k_gemm_nn_part(
    const float* __restrict__ A, int lda,
    const float* __restrict__ B, int ldb,
    float* __restrict__ part,
    int M, int N, int K, int kchunk)
{
  __shared__ float As[16][65];
  __shared__ float Bs[16][65];
  int bm = blockIdx.x * 64, bn = blockIdx.y * 64;
  int z = blockIdx.z;
  int ks = z * kchunk, ke = min(K, ks + kchunk);
  int tid = threadIdx.x;
  int tm = (tid >> 4) << 2, tn = (tid & 15) << 2;
  float acc[4][4] = {};
  for (int k0 = ks; k0 < ke; k0 += 16) {
    for (int i = tid; i < 1024; i += 256) {
      int m = i >> 4, k = i & 15;
      float v = 0.f;
      if (bm + m < M && k0 + k < ke) v = A[(size_t)(bm + m) * lda + k0 + k];
      As[k][m] = v;
    }
    for (int i = tid; i < 1024; i += 256) {
      int k = i >> 6, n = i & 63;
      float v = 0.f;
      if (k0 + k < ke && bn + n < N) v = B[(size_t)(k0 + k) * ldb + bn + n];
      Bs[k][n] = v;
    }
    __syncthreads();
#pragma unroll
    for (int kk = 0; kk < 16; ++kk) {
      float a[4], b[4];
#pragma unroll
      for (int i = 0; i < 4; i++) a[i] = As[kk][tm + i];
#pragma unroll
      for (int j = 0; j < 4; j++) b[j] = Bs[kk][tn + j];
#pragma unroll
      for (int i = 0; i < 4; i++)
#pragma unroll
        for (int j = 0; j < 4; j++) acc[i][j] += a[i] * b[j];
    }
    __syncthreads();
  }
  size_t base = (size_t)z * M * N;
#pragma unroll
  for (int i = 0; i < 4; i++) {
    int m = bm + tm + i; if (m >= M) continue;
#pragma unroll
    for (int j = 0; j < 4; j++) {
      int n = bn + tn + j; if (n >= N) continue;
      part[base + (size_t)m * N + n] = acc[i][j];
    }
  }
}

__global__ void k_reduce_bias(const float* __restrict__ part,
                              const float* __restrict__ bias,
                              float* __restrict__ C, int nparts, int M, int N)
{
  int idx = blockIdx.x * 256 + threadIdx.x;
  if (idx >= M * N) return;
  int n = idx % N;
  float s = 0.f;
  for (int p = 0; p < nparts; ++p) s += part[(size_t)p * M * N + idx];
  if (bias) s += bias[n];
  C[idx] = s;
}

// ---------------------------------------------------------------------------
// Small f32 TN GEMM with split-K + atomics (kept for the tiny x2 product)
// ---------------------------------------------------------------------------
__global__ __launch_bounds__(256) void k_gemm_tn(
    const float* __restrict__ A, int lda,
    const float* __restrict__ B, int ldb,
    float* __restrict__ C, int ldc,
    int M, int N, int K, int kchunk)
{
  __shared__ float As[16][65];
  __shared__ float Bs[16][65];
  int bm = blockIdx.x * 64, bn = blockIdx.y * 64;
  int ks = blockIdx.z * kchunk;
  int ke = min(K, ks + kchunk);
  int tid = threadIdx.x;
  int tm = (tid >> 4) << 2, tn = (tid & 15) << 2;
  float acc[4][4] = {};
  for (int k0 = ks; k0 < ke; k0 += 16) {
    for (int i = tid; i < 1024; i += 256) {
      int k = i >> 6, m = i & 63;
      float v = 0.f;
      if (k0 + k < ke && bm + m < M) v = A[(size_t)(k0 + k) * lda + bm + m];
      As[k][m] = v;
    }
    for (int i = tid; i < 1024; i += 256) {
      int k = i >> 6, n = i & 63;
      float v = 0.f;
      if (k0 + k < ke && bn + n < N) v = B[(size_t)(k0 + k) * ldb + bn + n];
      Bs[k][n] = v;
    }
    __syncthreads();
#pragma unroll
    for (int kk = 0; kk < 16; ++kk) {
      float a[4], b[4];
#pragma unroll
      for (int i = 0; i < 4; i++) a[i] = As[kk][tm + i];
#pragma unroll
      for (int j = 0; j < 4; j++) b[j] = Bs[kk][tn + j];
#pragma unroll
      for (int i = 0; i < 4; i++)
#pragma unroll
        for (int j = 0; j < 4; j++) acc[i][j] += a[i] * b[j];
    }
    __syncthreads();
  }
#pragma unroll
  for (int i = 0; i < 4; i++) {
    int m = bm + tm + i; if (m >= M) continue;
#pragma unroll
    for (int j = 0; j < 4; j++) {
      int n = bn + tn + j; if (n >= N) continue;
      atomicAdd(&C[(size_t)m * ldc + n], acc[i][j]);
    }
  }
}

// ---------------------------------------------------------------------------
// 64x64 f32 tile transpose + bf16 quantize: dst[c][r] = bf16(src[r][c])
// ---------------------------------------------------------------------------
__global__ __launch_bounds__(256) void k_transpose_bf16(
    const float* __restrict__ src, int R, int C,
    unsigned short* __restrict__ dst)
{
  __shared__ float tile[64][65];
  int br = blockIdx.x * 64, bc = blockIdx.y * 64;
  for (int idx = threadIdx.x; idx < 4096; idx += 256) {
    int r = idx >> 6, c = idx & 63;
    tile[r][c] = src[(size_t)(br + r) * C + bc + c];
  }
  __syncthreads();
  for (int idx = threadIdx.x; idx < 4096; idx += 256) {
    int c = idx >> 6, r = idx & 63;
    dst[(size_t)(bc + c) * R + br + r] = f2b(tile[r][c]);
  }
}

// ---------------------------------------------------------------------------
// bf16 MFMA NT GEMM: Cpart[z][M][N] = sum_k At[m][k]*Bt[n][k] over k-chunk z.
// ---------------------------------------------------------------------------
__global__ __launch_bounds__(256) void k_nt_bf16(
    const unsigned short* __restrict__ At,
    const unsigned short* __restrict__ Bt,
    float* __restrict__ Cpart,
    int M, int N, int K, int kchunk)
{
  __shared__ unsigned short Alds[64][136];  // pad 128->136 (272B rows, 16B aligned)
  __shared__ unsigned short Blds[64][136];
  const int bm = blockIdx.x * 64, bn = blockIdx.y * 64;
  const int z = blockIdx.z;
  const int k_beg = z * kchunk, k_end = k_beg + kchunk;
  const int tid = threadIdx.x;
  const int lane = tid & 63, wave = tid >> 6;
  const int lrow = lane & 15, lgrp = lane >> 4;
  f32x4 acc[4];
#pragma unroll
  for (int nt = 0; nt < 4; ++nt) acc[nt] = (f32x4){0.f, 0.f, 0.f, 0.f};

  for (int k0 = k_beg; k0 < k_end; k0 += 128) {
#pragma unroll
    for (int p = 0; p < 4; ++p) {
      int id = p * 256 + tid;
      int r = id >> 4;
      int c = id & 15;
      *(uint4*)(&Alds[r][c * 8]) =
          *(const uint4*)(At + (size_t)(bm + r) * K + k0 + c * 8);
      *(uint4*)(&Blds[r][c * 8]) =
          *(const uint4*)(Bt + (size_t)(bn + r) * K + k0 + c * 8);
    }
    __syncthreads();
#pragma unroll
    for (int kk = 0; kk < 4; ++kk) {
      short8 af = *(const short8*)(&Alds[wave * 16 + lrow][kk * 32 + lgrp * 8]);
#pragma unroll
      for (int nt = 0; nt < 4; ++nt) {
        short8 bf = *(const short8*)(&Blds[nt * 16 + lrow][kk * 32 + lgrp * 8]);
        acc[nt] = __builtin_amdgcn_mfma_f32_16x16x32_bf16(af, bf, acc[nt], 0, 0, 0);
      }
    }
    __syncthreads();
  }
  size_t base = (size_t)z * M * N;
#pragma unroll
  for (int nt = 0; nt < 4; ++nt) {
    int n = bn + nt * 16 + lrow;
#pragma unroll
    for (int r = 0; r < 4; ++r) {
      int m = bm + wave * 16 + lgrp * 4 + r;
      Cpart[base + (size_t)m * N + n] = acc[nt][r];
    }
  }
}

__global__ void k_reduce_parts(const float* __restrict__ part, float* __restrict__ C,
                               int nparts, int sz)
{
  int idx = blockIdx.x * 256 + threadIdx.x;
  if (idx >= sz) return;
  float s = 0.f;
  for (int p = 0; p < nparts; ++p) s += part[(size_t)p * sz + idx];
  C[idx] = s;
}

// ---------------------------------------------------------------------------
// CSR build
// ---------------------------------------------------------------------------
__global__ void k_count(const int* __restrict__ adj, int* __restrict__ counts)
{
  int e = blockIdx.x * 256 + threadIdx.x;
  if (e < EC) atomicAdd(&counts[adj[e]], 1);
}

__global__ __launch_bounds__(1024) void k_scan(const int* __restrict__ counts,
                                               int* __restrict__ offsets)
{
  __shared__ int tsum[1024];
  int tid = threadIdx.x;
  int base = tid * 8;
  int loc[8]; int s = 0;
#pragma unroll
  for (int i = 0; i < 8; i++) { loc[i] = s; s += counts[base + i]; }
  tsum[tid] = s;
  __syncthreads();
  for (int off = 1; off < 1024; off <<= 1) {
    int v = (tid >= off) ? tsum[tid - off] : 0;
    __syncthreads();
    tsum[tid] += v;
    __syncthreads();
  }
  int excl = (tid == 0) ? 0 : tsum[tid - 1];
#pragma unroll
  for (int i = 0; i < 8; i++) offsets[base + i] = excl + loc[i];
  if (tid == 1023) offsets[NC] = tsum[1023];
}

__global__ void k_scatter(const int* __restrict__ adj, const int* __restrict__ offsets,
                          int* __restrict__ fill, int* __restrict__ csr)
{
  int e = blockIdx.x * 256 + threadIdx.x;
  if (e < EC) {
    int d = adj[e], s = adj[EC + e];
    int p = atomicAdd(&fill[d], 1);
    csr[offsets[d] + p] = s;
  }
}

// ---------------------------------------------------------------------------
// Level-0 aggregation (WITH edge multiplicity)
// ---------------------------------------------------------------------------
__global__ __launch_bounds__(256) void k_agg0(
    const int* __restrict__ offsets, const int* __restrict__ csr,
    const float* __restrict__ sPre, const float* __restrict__ t0,
    const float* __restrict__ x,
    float* __restrict__ sAgg, float* __restrict__ z)
{
  int j = blockIdx.x;
  int beg = offsets[j], deg = offsets[j + 1] - beg;
  __shared__ int srcs[1024];
  bool inl = (deg <= 1024);
  if (inl) for (int i = threadIdx.x; i < deg; i += 256) srcs[i] = csr[beg + i];
  __syncthreads();
  for (int c = threadIdx.x; c < P0C; c += 256) {
    float acc = 0.f;
    for (int i = 0; i < deg; i++) {
      int s = inl ? srcs[i] : csr[beg + i];
      acc += sPre[(size_t)s * P0C + c];
    }
    sAgg[(size_t)j * P0C + c] = acc;
  }
  for (int c = threadIdx.x; c < ZIC; c += 256) {
    float acc = 0.f;
    for (int i = 0; i < deg; i++) {
      int s = inl ? srcs[i] : csr[beg + i];
      acc += t0[(size_t)s * ZIC + c];
    }
    z[(size_t)j * DC + 8 + c] = acc;
  }
  if (threadIdx.x < 8) z[(size_t)j * DC + threadIdx.x] = x[(size_t)j * DC + threadIdx.x];
}

// ---------------------------------------------------------------------------
// M = A0_dedup @ S0  (duplicate (dest,src) edges count once)
// ---------------------------------------------------------------------------
__global__ __launch_bounds__(256) void k_aggM(
    const int* __restrict__ offsets, const int* __restrict__ csr,
    const float* __restrict__ S0, float* __restrict__ M)
{
  int j = blockIdx.x;
  int beg = offsets[j], deg = offsets[j + 1] - beg;
  __shared__ int srcs[1024];
  bool inl = (deg <= 1024);
  if (inl) for (int i = threadIdx.x; i < deg; i += 256) srcs[i] = csr[beg + i];
  __syncthreads();
  if (inl) {
    for (int t = threadIdx.x; t < deg; t += 256) {
      int v = srcs[t];
      for (int u = 0; u < t; ++u)
        if (csr[beg + u] == v) { srcs[t] = -1; break; }
    }
  }
  __syncthreads();
  for (int c = threadIdx.x; c < P0C; c += 256) {
    float acc = 0.f;
    for (int i = 0; i < deg; i++) {
      int s = inl ? srcs[i] : csr[beg + i];
      if (!inl) {
        bool dup = false;
        for (int u = 0; u < i; u++) if (csr[beg + u] == s) { dup = true; break; }
        if (dup) s = -1;
      }
      if (s >= 0) acc += S0[(size_t)s * P0C + c];
    }
    M[(size_t)j * P0C + c] = acc;
  }
}

// ---------------------------------------------------------------------------
// Fused expmap0/logmap0 row scale
// ---------------------------------------------------------------------------
__global__ __launch_bounds__(256) void k_rowscale(const float* __restrict__ U, int cols,
                                                  float* __restrict__ rs)
{
  int r = blockIdx.x;
  const float* row = U + (size_t)r * cols;
  float ss = 0.f;
  for (int c = threadIdx.x; c < cols; c += 256) { float v = row[c]; ss += v * v; }
  for (int off = 32; off > 0; off >>= 1) ss += __shfl_down(ss, off);
  __shared__ float red[4];
  if ((threadIdx.x & 63) == 0) red[threadIdx.x >> 6] = ss;
  __syncthreads();
  if (threadIdx.x == 0) {
    float n = sqrtf(red[0] + red[1] + red[2] + red[3]);
    n = fmaxf(n, 1e-15f);
    rs[r] = TEMPC * fminf(n, ATANH_MAX) / n;
  }
}

// ---------------------------------------------------------------------------
// Column softmax (axis=0), two-stage online
// ---------------------------------------------------------------------------
__global__ __launch_bounds__(256) void k_smaxA(const float* __restrict__ U,
    const float* __restrict__ rs, float* __restrict__ pm, float* __restrict__ ps,
    int rows, int cols, int rpg)
{
  int lc = threadIdx.x & 63;
  int c = blockIdx.x * 64 + lc;
  int rl = threadIdx.x >> 6;
  int r0 = blockIdx.y * rpg, r1 = min(rows, r0 + rpg);
  float m = -1e30f, s = 0.f;
  for (int r = r0 + rl; r < r1; r += 4) {
    float l = rs[r] * U[(size_t)r * cols + c];
    if (l > m) { s = s * __expf(m - l) + 1.f; m = l; }
    else s += __expf(l - m);
  }
  __shared__ float sm[4][64], sv[4][64];
  sm[rl][lc] = m; sv[rl][lc] = s;
  __syncthreads();
  if (threadIdx.x < 64) {
    float mm = sm[0][threadIdx.x], s2 = sv[0][threadIdx.x];
    for (int q = 1; q < 4; q++) {
      float mq = sm[q][threadIdx.x], sq = sv[q][threadIdx.x];
      float mn = fmaxf(mm, mq);
      s2 = s2 * __expf(mm - mn) + sq * __expf(mq - mn);
      mm = mn;
    }
    pm[(size_t)blockIdx.y * cols + blockIdx.x * 64 + threadIdx.x] = mm;
    ps[(size_t)blockIdx.y * cols + blockIdx.x * 64 + threadIdx.x] = s2;
  }
}

__global__ void k_smaxB(const float* __restrict__ pm, const float* __restrict__ ps,
                        float* __restrict__ colm, float* __restrict__ colsum,
                        int ng, int cols)
{
  int c = blockIdx.x * blockDim.x + threadIdx.x;
  if (c >= cols) return;
  float m = -1e30f, s = 0.f;
  for (int g = 0; g < ng; g++) {
    float mg = pm[(size_t)g * cols + c], sg = ps[(size_t)g * cols + c];
    float mn = fmaxf(m, mg);
    s = s * __expf(m - mn) + sg * __expf(mg - mn);
    m = mn;
  }
  colm[c] = m; colsum[c] = s;
}

__global__ __launch_bounds__(256) void k_smaxC(const float* __restrict__ U,
    const float* __restrict__ rs, const float* __restrict__ colm,
    const float* __restrict__ colsum, float* __restrict__ S,
    float* __restrict__ loss, int rows, int cols, int rpg)
{
  int lc = threadIdx.x & 63;
  int c = blockIdx.x * 64 + lc;
  int rl = threadIdx.x >> 6;
  int r0 = blockIdx.y * rpg, r1 = min(rows, r0 + rpg);
  float m = colm[c], inv = 1.f / colsum[c];
  float h = 0.f;
  for (int r = r0 + rl; r < r1; r += 4) {
    float l = rs[r] * U[(size_t)r * cols + c];
    float p = __expf(l - m) * inv;
    S[(size_t)r * cols + c] = p;
    if (p > 0.f) h -= p * __logf(p);
  }
  for (int off = 32; off > 0; off >>= 1) h += __shfl_down(h, off);
  __shared__ float red[4];
  if ((threadIdx.x & 63) == 0) red[threadIdx.x >> 6] = h;
  __syncthreads();
  if (threadIdx.x == 0) atomicAdd(loss, red[0] + red[1] + red[2] + red[3]);
}

// single-stage small column softmax (level 1: 512 rows)
__global__ __launch_bounds__(256) void k_smax_small(const float* __restrict__ U,
    const float* __restrict__ rs, float* __restrict__ S, float* __restrict__ loss,
    int rows, int cols)
{
  int lc = threadIdx.x & 63;
  int c = blockIdx.x * 64 + lc;
  int rl = threadIdx.x >> 6;
  float m = -1e30f, s = 0.f;
  for (int r = rl; r < rows; r += 4) {
    float l = rs[r] * U[(size_t)r * cols + c];
    if (l > m) { s = s * __expf(m - l) + 1.f; m = l; }
    else s += __expf(l - m);
  }
  __shared__ float sm[4][64], sv[4][64], fm[64], fs[64];
  sm[rl][lc] = m; sv[rl][lc] = s;
  __syncthreads();
  if (threadIdx.x < 64) {
    float mm = sm[0][threadIdx.x], s2 = sv[0][threadIdx.x];
    for (int q = 1; q < 4; q++) {
      float mq = sm[q][threadIdx.x], sq = sv[q][threadIdx.x];
      float mn = fmaxf(mm, mq);
      s2 = s2 * __expf(mm - mn) + sq * __expf(mq - mn);
      mm = mn;
    }
    fm[threadIdx.x] = mm; fs[threadIdx.x] = s2;
  }
  __syncthreads();
  float M0 = fm[lc], inv = 1.f / fs[lc];
  float h = 0.f;
  for (int r = rl; r < rows; r += 4) {
    float l = rs[r] * U[(size_t)r * cols + c];
    float p = __expf(l - M0) * inv;
    S[(size_t)r * cols + c] = p;
    if (p > 0.f) h -= p * __logf(p);
  }
  for (int off = 32; off > 0; off >>= 1) h += __shfl_down(h, off);
  if ((threadIdx.x & 63) == 0) atomicAdd(loss, h);
}

// ---------------------------------------------------------------------------
// y-projection via split-K partials
// ---------------------------------------------------------------------------
__global__ __launch_bounds__(256) void k_yS_part(
    const float* __restrict__ Y, int ldy,
    const float* __restrict__ S, int ldS,
    float* __restrict__ part, int K, int C, int kchunk)
{
  int lc = threadIdx.x & 63;
  int c = blockIdx.x * 64 + lc;
  int rl = threadIdx.x >> 6;
  int r0 = blockIdx.y * kchunk, r1 = min(K, r0 + kchunk);
  float acc[8] = {};
  for (int r = r0 + rl; r < r1; r += 4) {
    float sv = S[(size_t)r * ldS + c];
#pragma unroll
    for (int t = 0; t < 8; t++) acc[t] += Y[(size_t)t * ldy + r] * sv;
  }
  __shared__ float red[4][8][64];
#pragma unroll
  for (int t = 0; t < 8; t++) red[rl][t][lc] = acc[t];
  __syncthreads();
  if (rl == 0) {
#pragma unroll
    for (int t = 0; t < 8; t++) {
      float v = red[0][t][lc] + red[1][t][lc] + red[2][t][lc] + red[3][t][lc];
      part[((size_t)blockIdx.y * 8 + t) * C + c] = v;
    }
  }
}

__global__ void k_yS_red(const float* __restrict__ part, float* __restrict__ outp,
                         int nparts, int sz)
{
  int idx = blockIdx.x * 256 + threadIdx.x;
  if (idx >= sz) return;
  float s = 0.f;
  for (int p = 0; p < nparts; ++p) s += part[(size_t)p * sz + idx];
  outp[idx] = s;
}

__global__ void k_zbuild1(const float* __restrict__ x1f, const float* __restrict__ zi1,
                          float* __restrict__ z1)
{
  int idx = blockIdx.x * 256 + threadIdx.x;
  if (idx >= P0C * DC) return;
  int r = idx >> 7, c = idx & 127;
  z1[idx] = (c < 8) ? x1f[idx] : zi1[r * ZIC + c - 8];
}

// f32 -> f32 copy/emit with independent src/dst leading dims
__global__ void k_emit(const float* __restrict__ src, int lsrc,
                       float* __restrict__ dst, int ldd, int rows, int cols)
{
  int idx = blockIdx.x * 256 + threadIdx.x;
  if (idx >= rows * cols) return;
  int r = idx / cols, c = idx - r * cols;
  dst[(size_t)r * ldd + c] = src[(size_t)r * lsrc + c];
}

// ---------------------------------------------------------------------------
extern "C" void kernel_launch(void* const* d_in, const int* in_sizes, int n_in,
                              void* d_out, int out_size, void* d_ws, size_t ws_size,
                              hipStream_t stream)
{
  (void)in_sizes; (void)n_in; (void)out_size; (void)ws_size;
  const float* x   = (const float*)d_in[0];
  const float* y   = (const float*)d_in[1];
  const float* We0 = (const float*)d_in[2];
  const float* be0 = (const float*)d_in[3];
  const float* Ws0 = (const float*)d_in[4];
  const float* bs0 = (const float*)d_in[5];
  const float* We1 = (const float*)d_in[6];
  const float* be1 = (const float*)d_in[7];
  const float* Ws1 = (const float*)d_in[8];
  const float* bs1 = (const float*)d_in[9];
  const int*   adj = (const int*)d_in[10];
  float* out = (float*)d_out;

  float* ws = (float*)d_ws;
  size_t o = 0;
  auto alloc = [&](size_t n) { float* p = ws + o; o += n; return p; };
  float* t0    = alloc((size_t)NC * ZIC);
  float* sPre  = alloc((size_t)NC * P0C);   // reused as S0 after softmax
  float* sAgg  = alloc((size_t)NC * P0C);   // reused as Mb, then as A1 partials
  float* zbuf  = alloc((size_t)NC * DC);    // reused as x1 partials
  float* rsc   = alloc(NC);
  float* pm    = alloc(32 * P0C);
  float* ps    = alloc(32 * P0C);
  float* colm  = alloc(P0C);
  float* colsum= alloc(P0C);
  float* t1    = alloc((size_t)P0C * ZIC);
  float* s1pre = alloc((size_t)P0C * P1C);
  float* zi1   = alloc((size_t)P0C * ZIC);
  float* s1agg = alloc((size_t)P0C * P1C);
  float* S1    = alloc((size_t)P0C * P1C);
  float* z1    = alloc((size_t)P0C * P1C);
  float* rs1   = alloc(P0C);
  float* x1f   = alloc((size_t)P0C * DC);      // written by reduce (no memset)
  float* A1    = alloc((size_t)P0C * P0C);     // written by reduce (no memset)
  unsigned short* S0T   = (unsigned short*)alloc((size_t)P0C * NC / 2); // 512x8192 bf16
  unsigned short* MbT   = (unsigned short*)alloc((size_t)P0C * NC / 2); // 512x8192 bf16
  unsigned short* zbufT = (unsigned short*)alloc((size_t)DC * NC / 2);  // 128x8192 bf16
  float* partY1 = alloc((size_t)128 * TC * P0C);  // 128 chunks x 8 x 512
  float* partY2 = alloc((size_t)8 * TC * P1C);    // 8 chunks x 8 x 128
  float* partL1a = alloc((size_t)2 * P0C * ZIC);  // t1 partials (KB=2)
  float* partL1b = alloc((size_t)2 * P0C * P1C);  // s1pre partials (KB=2)
  float* partL1c = alloc((size_t)8 * P0C * ZIC);  // zi1 partials (KB=8)
  float* partL1d = alloc((size_t)8 * P0C * P1C);  // s1agg partials (KB=8)
  // atomic-accumulated zone (contiguous, zeroed every call)
  float* x2f   = alloc((size_t)P1C * DC);
  float* y1f   = alloc((size_t)TC * P0C);
  float* y2f   = alloc((size_t)TC * P1C);
  float* lossf = alloc(1);
  size_t atomicFloats = (size_t)P1C*DC + (size_t)TC*P0C + (size_t)TC*P1C + 1;
  o = (o + 63) & ~(size_t)63;
  int* ibase   = (int*)(ws + o);
  int* counts  = ibase;
  int* fill    = ibase + NC;
  int* offsets = ibase + 2 * NC;
  int* csr     = ibase + 2 * NC + (NC + 1);

  float* S0 = sPre;        // alias: sPre dead after k_agg0
  float* Mb = sAgg;        // alias: sAgg dead after S0T/smax done
  float* partsA1 = sAgg;   // alias: Mb dead after MbT transpose (8*512*512 <= NC*P0C)
  float* partsX1 = zbuf;   // alias: zbuf dead after zbufT transpose (16*512*128 == NC*DC)

  hipMemsetAsync(x2f, 0, atomicFloats * sizeof(float), stream);
  hipMemsetAsync(counts, 0, 2 * NC * sizeof(int), stream);

  // ---- level 0 transforms ----
  k_gemm_nn<<<dim3(NC/64, (ZIC+63)/64), 256, 0, stream>>>(x + 8, DC, We0, ZIC, be0, t0, ZIC, NC, ZIC, ZIC);
  k_gemm_nn<<<dim3(NC/64, P0C/64), 256, 0, stream>>>(x, DC, Ws0, P0C, bs0, sPre, P0C, NC, P0C, DC);

  // ---- CSR build ----
  k_count  <<<EC/256, 256, 0, stream>>>(adj, counts);
  k_scan   <<<1, 1024, 0, stream>>>(counts, offsets);
  k_scatter<<<EC/256, 256, 0, stream>>>(adj, offsets, fill, csr);

  // ---- aggregation (with multiplicity) + z assembly ----
  k_agg0<<<NC, 256, 0, stream>>>(offsets, csr, sPre, t0, x, sAgg, zbuf);
  k_transpose_bf16<<<dim3(NC/64, DC/64), 256, 0, stream>>>(zbuf, NC, DC, zbufT);

  // ---- fused expmap/logmap + column softmax -> S0, entropy ----
  k_rowscale<<<NC, 256, 0, stream>>>(sAgg, P0C, rsc);
  k_smaxA<<<dim3(P0C/64, 32), 256, 0, stream>>>(sAgg, rsc, pm, ps, NC, P0C, 256);
  k_smaxB<<<P0C/256, 256, 0, stream>>>(pm, ps, colm, colsum, 32, P0C);
  k_smaxC<<<dim3(P0C/64, 32), 256, 0, stream>>>(sAgg, rsc, colm, colsum, S0, lossf, NC, P0C, 256);
  k_transpose_bf16<<<dim3(NC/64, P0C/64), 256, 0, stream>>>(S0, NC, P0C, S0T);

  // ---- M = A0_dedup @ S0 ; transpose ----
  k_aggM<<<NC, 256, 0, stream>>>(offsets, csr, S0, Mb);
  k_transpose_bf16<<<dim3(NC/64, P0C/64), 256, 0, stream>>>(Mb, NC, P0C, MbT);

  // ---- pooled products via bf16 MFMA (split-K partials + reduce) ----
  // A1 = S0^T @ Mb : M=512 N=512 K=8192, Z=8 (kchunk 1024)
  k_nt_bf16<<<dim3(P0C/64, P0C/64, 8), 256, 0, stream>>>(S0T, MbT, partsA1, P0C, P0C, NC, 1024);
  k_reduce_parts<<<(P0C*P0C)/256, 256, 0, stream>>>(partsA1, A1, 8, P0C*P0C);
  // x1 = S0^T @ z : M=512 N=128 K=8192, Z=16 (kchunk 512)
  k_nt_bf16<<<dim3(P0C/64, DC/64, 16), 256, 0, stream>>>(S0T, zbufT, partsX1, P0C, DC, NC, 512);
  k_reduce_parts<<<(P0C*DC)/256, 256, 0, stream>>>(partsX1, x1f, 16, P0C*DC);
  // y1 = y @ S0 : split-K partials (128 chunks of 64 rows) + reduce
  k_yS_part<<<dim3(P0C/64, 128), 256, 0, stream>>>(y, NC, S0, P0C, partY1, NC, P0C, 64);
  k_yS_red<<<(TC*P0C + 255)/256, 256, 0, stream>>>(partY1, y1f, 128, TC*P0C);

  // ---- level 1 (split-K f32, latency-bound fix) ----
  // t1 = x1[:,8:] @ We1 + be1 : M=512 N=120 K=120, KB=2
  k_gemm_nn_part<<<dim3(P0C/64, 2, 2), 256, 0, stream>>>(x1f + 8, DC, We1, ZIC, partL1a, P0C, ZIC, ZIC, 64);
  k_reduce_bias<<<(P0C*ZIC + 255)/256, 256, 0, stream>>>(partL1a, be1, t1, 2, P0C, ZIC);
  // s1pre = x1 @ Ws1 + bs1 : M=512 N=128 K=128, KB=2
  k_gemm_nn_part<<<dim3(P0C/64, P1C/64, 2), 256, 0, stream>>>(x1f, DC, Ws1, P1C, partL1b, P0C, P1C, DC, 64);
  k_reduce_bias<<<(P0C*P1C + 255)/256, 256, 0, stream>>>(partL1b, bs1, s1pre, 2, P0C, P1C);
  // zi1 = A1 @ t1 : M=512 N=120 K=512, KB=8
  k_gemm_nn_part<<<dim3(P0C/64, 2, 8), 256, 0, stream>>>(A1, P0C, t1, ZIC, partL1c, P0C, ZIC, P0C, 64);
  k_reduce_bias<<<(P0C*ZIC + 255)/256, 256, 0, stream>>>(partL1c, nullptr, zi1, 8, P0C, ZIC);
  // s1agg = A1 @ s1pre : M=512 N=128 K=512, KB=8
  k_gemm_nn_part<<<dim3(P0C/64, P1C/64, 8), 256, 0, stream>>>(A1, P0C, s1pre, P1C, partL1d, P0C, P1C, P0C, 64);
  k_reduce_bias<<<(P0C*P1C + 255)/256, 256, 0, stream>>>(partL1d, nullptr, s1agg, 8, P0C, P1C);

  k_zbuild1<<<(P0C*DC + 255)/256, 256, 0, stream>>>(x1f, zi1, z1);
  k_rowscale<<<P0C, 256, 0, stream>>>(s1agg, P1C, rs1);
  k_smax_small<<<P1C/64, 256, 0, stream>>>(s1agg, rs1, S1, lossf, P0C, P1C);
  k_gemm_tn<<<dim3(P1C/64, DC/64, 4), 256, 0, stream>>>(S1, P1C, z1, DC, x2f, DC, P1C, DC, P0C, 128);
  // y2 = y1 @ S1 : split-K partials (8 chunks of 64 rows) + reduce
  k_yS_part<<<dim3(P1C/64, 8), 256, 0, stream>>>(y1f, P0C, S1, P1C, partY2, P0C, P1C, 64);
  k_yS_red<<<(TC*P1C + 255)/256, 256, 0, stream>>>(partY2, y2f, 8, TC*P1C);

  // ---- emit outputs (f32) ----
  const size_t yr_off = (size_t)(NC + P0C + P1C) * DC;  // 1130496
  const int YW = NC + P0C + P1C;                        // 8832
  k_emit<<<(NC*DC + 255)/256, 256, 0, stream>>>(x, DC, out, DC, NC, DC);
  k_emit<<<(P0C*DC + 255)/256, 256, 0, stream>>>(x1f, DC, out + (size_t)NC*DC, DC, P0C, DC);
  k_emit<<<(P1C*DC + 255)/256, 256, 0, stream>>>(x2f, DC, out + (size_t)(NC+P0C)*DC, DC, P1C, DC);
  k_emit<<<(TC*NC + 255)/256, 256, 0, stream>>>(y, NC, out + yr_off, YW, TC, NC);
  k_emit<<<(TC*P0C + 255)/256, 256, 0, stream>>>(y1f, P0C, out + yr_off + NC, YW, TC, P0C);
  k_emit<<<(TC*P1C + 255)/256, 256, 0, stream>>>(y2f, P1C, out + yr_off + NC + P0C, YW, TC, P1C);
  k_emit<<<1, 256, 0, stream>>>(lossf, 1, out + yr_off + (size_t)TC*YW, 1, 1, 1);
}

// Round 6
// 485.974 us; speedup vs baseline: 2.1944x; 1.1421x over previous
//
#include <hip/hip_runtime.h>
#include <hip/hip_bf16.h>

// Problem constants
#define NC   8192
#define EC   131072
#define DC   128
#define TC   8
#define P0C  512
#define P1C  128
#define ZIC  120
#define TEMPC 200.0f
// atanh(float32(1 - 1e-5)) = atanh(0.99999004602432251) -- matches JAX's f32 clip
#define ATANH_MAX 6.1053405f

typedef short short8 __attribute__((ext_vector_type(8)));
typedef float f32x4 __attribute__((ext_vector_type(4)));

__device__ inline unsigned short f2b(float f) {  // f32 -> bf16 bits, RNE
  union { float f; unsigned u; } x; x.f = f;
  unsigned r = x.u + 0x7FFFu + ((x.u >> 16) & 1u);
  return (unsigned short)(r >> 16);
}
__device__ inline float b2f(unsigned short b) {
  union { unsigned u; float f; } x; x.u = ((unsigned)b) << 16; return x.f;
}

// ---------------------------------------------------------------------------
// Tiled f32 GEMM with deg-scaled bias:  C[M,N] = A@B + degf[m]*bias[n]
// ---------------------------------------------------------------------------
__global__ __launch_bounds__(256) void k_gemm_nn_degbias(
    const float* __restrict__ A, int lda,
    const float* __restrict__ B, int ldb,
    const float* __restrict__ bias,
    const float* __restrict__ degf,
    float* __restrict__ C, int ldc,
    int M, int N, int K)
{
  __shared__ float As[16][65];
  __shared__ float Bs[16][65];
  int bm = blockIdx.x * 64, bn = blockIdx.y * 64;
  int tid = threadIdx.x;
  int tm = (tid >> 4) << 2, tn = (tid & 15) << 2;
  float acc[4][4] = {};
  for (int k0 = 0; k0 < K; k0 += 16) {
    for (int i = tid; i < 1024; i += 256) {
      int m = i >> 4, k = i & 15;
      float v = 0.f;
      if (bm + m < M && k0 + k < K) v = A[(size_t)(bm + m) * lda + k0 + k];
      As[k][m] = v;
    }
    for (int i = tid; i < 1024; i += 256) {
      int k = i >> 6, n = i & 63;
      float v = 0.f;
      if (k0 + k < K && bn + n < N) v = B[(size_t)(k0 + k) * ldb + bn + n];
      Bs[k][n] = v;
    }
    __syncthreads();
#pragma unroll
    for (int kk = 0; kk < 16; ++kk) {
      float a[4], b[4];
#pragma unroll
      for (int i = 0; i < 4; i++) a[i] = As[kk][tm + i];
#pragma unroll
      for (int j = 0; j < 4; j++) b[j] = Bs[kk][tn + j];
#pragma unroll
      for (int i = 0; i < 4; i++)
#pragma unroll
        for (int j = 0; j < 4; j++) acc[i][j] += a[i] * b[j];
    }
    __syncthreads();
  }
#pragma unroll
  for (int i = 0; i < 4; i++) {
    int m = bm + tm + i; if (m >= M) continue;
    float dg = degf ? degf[m] : 1.f;
#pragma unroll
    for (int j = 0; j < 4; j++) {
      int n = bn + tn + j; if (n >= N) continue;
      float v = acc[i][j];
      if (bias) v += dg * bias[n];
      C[(size_t)m * ldc + n] = v;
    }
  }
}

// ---------------------------------------------------------------------------
// f32 NN GEMM, split-K partials (level-1 small GEMMs)
// ---------------------------------------------------------------------------
__global__ __launch_bounds__(256) void k_gemm_nn_part(
    const float* __restrict__ A, int lda,
    const float* __restrict__ B, int ldb,
    float* __restrict__ part,
    int M, int N, int K, int kchunk)
{
  __shared__ float As[16][65];
  __shared__ float Bs[16][65];
  int bm = blockIdx.x * 64, bn = blockIdx.y * 64;
  int z = blockIdx.z;
  int ks = z * kchunk, ke = min(K, ks + kchunk);
  int tid = threadIdx.x;
  int tm = (tid >> 4) << 2, tn = (tid & 15) << 2;
  float acc[4][4] = {};
  for (int k0 = ks; k0 < ke; k0 += 16) {
    for (int i = tid; i < 1024; i += 256) {
      int m = i >> 4, k = i & 15;
      float v = 0.f;
      if (bm + m < M && k0 + k < ke) v = A[(size_t)(bm + m) * lda + k0 + k];
      As[k][m] = v;
    }
    for (int i = tid; i < 1024; i += 256) {
      int k = i >> 6, n = i & 63;
      float v = 0.f;
      if (k0 + k < ke && bn + n < N) v = B[(size_t)(k0 + k) * ldb + bn + n];
      Bs[k][n] = v;
    }
    __syncthreads();
#pragma unroll
    for (int kk = 0; kk < 16; ++kk) {
      float a[4], b[4];
#pragma unroll
      for (int i = 0; i < 4; i++) a[i] = As[kk][tm + i];
#pragma unroll
      for (int j = 0; j < 4; j++) b[j] = Bs[kk][tn + j];
#pragma unroll
      for (int i = 0; i < 4; i++)
#pragma unroll
        for (int j = 0; j < 4; j++) acc[i][j] += a[i] * b[j];
    }
    __syncthreads();
  }
  size_t base = (size_t)z * M * N;
#pragma unroll
  for (int i = 0; i < 4; i++) {
    int m = bm + tm + i; if (m >= M) continue;
#pragma unroll
    for (int j = 0; j < 4; j++) {
      int n = bn + tn + j; if (n >= N) continue;
      part[base + (size_t)m * N + n] = acc[i][j];
    }
  }
}

__global__ void k_reduce_bias(const float* __restrict__ part,
                              const float* __restrict__ bias,
                              float* __restrict__ C, int nparts, int M, int N)
{
  int idx = blockIdx.x * 256 + threadIdx.x;
  if (idx >= M * N) return;
  int n = idx % N;
  float s = 0.f;
  for (int p = 0; p < nparts; ++p) s += part[(size_t)p * M * N + idx];
  if (bias) s += bias[n];
  C[idx] = s;
}

// ---------------------------------------------------------------------------
// Small f32 TN GEMM with split-K + atomics (x2 product)
// ---------------------------------------------------------------------------
__global__ __launch_bounds__(256) void k_gemm_tn(
    const float* __restrict__ A, int lda,
    const float* __restrict__ B, int ldb,
    float* __restrict__ C, int ldc,
    int M, int N, int K, int kchunk)
{
  __shared__ float As[16][65];
  __shared__ float Bs[16][65];
  int bm = blockIdx.x * 64, bn = blockIdx.y * 64;
  int ks = blockIdx.z * kchunk;
  int ke = min(K, ks + kchunk);
  int tid = threadIdx.x;
  int tm = (tid >> 4) << 2, tn = (tid & 15) << 2;
  float acc[4][4] = {};
  for (int k0 = ks; k0 < ke; k0 += 16) {
    for (int i = tid; i < 1024; i += 256) {
      int k = i >> 6, m = i & 63;
      float v = 0.f;
      if (k0 + k < ke && bm + m < M) v = A[(size_t)(k0 + k) * lda + bm + m];
      As[k][m] = v;
    }
    for (int i = tid; i < 1024; i += 256) {
      int k = i >> 6, n = i & 63;
      float v = 0.f;
      if (k0 + k < ke && bn + n < N) v = B[(size_t)(k0 + k) * ldb + bn + n];
      Bs[k][n] = v;
    }
    __syncthreads();
#pragma unroll
    for (int kk = 0; kk < 16; ++kk) {
      float a[4], b[4];
#pragma unroll
      for (int i = 0; i < 4; i++) a[i] = As[kk][tm + i];
#pragma unroll
      for (int j = 0; j < 4; j++) b[j] = Bs[kk][tn + j];
#pragma unroll
      for (int i = 0; i < 4; i++)
#pragma unroll
        for (int j = 0; j < 4; j++) acc[i][j] += a[i] * b[j];
    }
    __syncthreads();
  }
#pragma unroll
  for (int i = 0; i < 4; i++) {
    int m = bm + tm + i; if (m >= M) continue;
#pragma unroll
    for (int j = 0; j < 4; j++) {
      int n = bn + tn + j; if (n >= N) continue;
      atomicAdd(&C[(size_t)m * ldc + n], acc[i][j]);
    }
  }
}

// ---------------------------------------------------------------------------
// 64x64 f32 tile transpose + bf16 quantize: dst[c][r] = bf16(src[r][c])
// ---------------------------------------------------------------------------
__global__ __launch_bounds__(256) void k_transpose_bf16(
    const float* __restrict__ src, int R, int C,
    unsigned short* __restrict__ dst)
{
  __shared__ float tile[64][65];
  int br = blockIdx.x * 64, bc = blockIdx.y * 64;
  for (int idx = threadIdx.x; idx < 4096; idx += 256) {
    int r = idx >> 6, c = idx & 63;
    tile[r][c] = src[(size_t)(br + r) * C + bc + c];
  }
  __syncthreads();
  for (int idx = threadIdx.x; idx < 4096; idx += 256) {
    int c = idx >> 6, r = idx & 63;
    dst[(size_t)(bc + c) * R + br + r] = f2b(tile[r][c]);
  }
}

// ---------------------------------------------------------------------------
// bf16 MFMA NT GEMM: Cpart[z][M][N] = sum_k At[m][k]*Bt[n][k] over k-chunk z.
// ---------------------------------------------------------------------------
__global__ __launch_bounds__(256) void k_nt_bf16(
    const unsigned short* __restrict__ At,
    const unsigned short* __restrict__ Bt,
    float* __restrict__ Cpart,
    int M, int N, int K, int kchunk)
{
  __shared__ unsigned short Alds[64][136];
  __shared__ unsigned short Blds[64][136];
  const int bm = blockIdx.x * 64, bn = blockIdx.y * 64;
  const int z = blockIdx.z;
  const int k_beg = z * kchunk, k_end = k_beg + kchunk;
  const int tid = threadIdx.x;
  const int lane = tid & 63, wave = tid >> 6;
  const int lrow = lane & 15, lgrp = lane >> 4;
  f32x4 acc[4];
#pragma unroll
  for (int nt = 0; nt < 4; ++nt) acc[nt] = (f32x4){0.f, 0.f, 0.f, 0.f};

  for (int k0 = k_beg; k0 < k_end; k0 += 128) {
#pragma unroll
    for (int p = 0; p < 4; ++p) {
      int id = p * 256 + tid;
      int r = id >> 4;
      int c = id & 15;
      *(uint4*)(&Alds[r][c * 8]) =
          *(const uint4*)(At + (size_t)(bm + r) * K + k0 + c * 8);
      *(uint4*)(&Blds[r][c * 8]) =
          *(const uint4*)(Bt + (size_t)(bn + r) * K + k0 + c * 8);
    }
    __syncthreads();
#pragma unroll
    for (int kk = 0; kk < 4; ++kk) {
      short8 af = *(const short8*)(&Alds[wave * 16 + lrow][kk * 32 + lgrp * 8]);
#pragma unroll
      for (int nt = 0; nt < 4; ++nt) {
        short8 bf = *(const short8*)(&Blds[nt * 16 + lrow][kk * 32 + lgrp * 8]);
        acc[nt] = __builtin_amdgcn_mfma_f32_16x16x32_bf16(af, bf, acc[nt], 0, 0, 0);
      }
    }
    __syncthreads();
  }
  size_t base = (size_t)z * M * N;
#pragma unroll
  for (int nt = 0; nt < 4; ++nt) {
    int n = bn + nt * 16 + lrow;
#pragma unroll
    for (int r = 0; r < 4; ++r) {
      int m = bm + wave * 16 + lgrp * 4 + r;
      Cpart[base + (size_t)m * N + n] = acc[nt][r];
    }
  }
}

__global__ void k_reduce_parts(const float* __restrict__ part, float* __restrict__ C,
                               int nparts, int sz)
{
  int idx = blockIdx.x * 256 + threadIdx.x;
  if (idx >= sz) return;
  float s = 0.f;
  for (int p = 0; p < nparts; ++p) s += part[(size_t)p * sz + idx];
  C[idx] = s;
}

// ---------------------------------------------------------------------------
// CSR build
// ---------------------------------------------------------------------------
__global__ void k_count(const int* __restrict__ adj, int* __restrict__ counts)
{
  int e = blockIdx.x * 256 + threadIdx.x;
  if (e < EC) atomicAdd(&counts[adj[e]], 1);
}

__global__ __launch_bounds__(1024) void k_scan(const int* __restrict__ counts,
                                               int* __restrict__ offsets)
{
  __shared__ int tsum[1024];
  int tid = threadIdx.x;
  int base = tid * 8;
  int loc[8]; int s = 0;
#pragma unroll
  for (int i = 0; i < 8; i++) { loc[i] = s; s += counts[base + i]; }
  tsum[tid] = s;
  __syncthreads();
  for (int off = 1; off < 1024; off <<= 1) {
    int v = (tid >= off) ? tsum[tid - off] : 0;
    __syncthreads();
    tsum[tid] += v;
    __syncthreads();
  }
  int excl = (tid == 0) ? 0 : tsum[tid - 1];
#pragma unroll
  for (int i = 0; i < 8; i++) offsets[base + i] = excl + loc[i];
  if (tid == 1023) offsets[NC] = tsum[1023];
}

__global__ void k_scatter(const int* __restrict__ adj, const int* __restrict__ offsets,
                          int* __restrict__ fill, int* __restrict__ csr)
{
  int e = blockIdx.x * 256 + threadIdx.x;
  if (e < EC) {
    int d = adj[e], s = adj[EC + e];
    int p = atomicAdd(&fill[d], 1);
    csr[offsets[d] + p] = s;
  }
}

__global__ void k_degf(const int* __restrict__ counts, float* __restrict__ degf)
{
  int i = blockIdx.x * 256 + threadIdx.x;
  if (i < NC) degf[i] = (float)counts[i];
}

// ---------------------------------------------------------------------------
// Aggregate raw x rows (with multiplicity): xa[j,:] = sum_{e: dst=j} x[src_e,:]
// Also copies z[j, 0:8] = x[j, 0:8]. Block = 128 threads (one col each).
// ---------------------------------------------------------------------------
__global__ __launch_bounds__(128) void k_aggX(
    const int* __restrict__ offsets, const int* __restrict__ csr,
    const float* __restrict__ x,
    float* __restrict__ xa, float* __restrict__ z)
{
  int j = blockIdx.x;
  int beg = offsets[j], deg = offsets[j + 1] - beg;
  __shared__ int srcs[512];
  bool inl = (deg <= 512);
  if (inl) for (int i = threadIdx.x; i < deg; i += 128) srcs[i] = csr[beg + i];
  __syncthreads();
  int c = threadIdx.x;
  float acc = 0.f;
  for (int i = 0; i < deg; i++) {
    int s = inl ? srcs[i] : csr[beg + i];
    acc += x[(size_t)s * DC + c];
  }
  xa[(size_t)j * DC + c] = acc;
  if (c < 8) z[(size_t)j * DC + c] = x[(size_t)j * DC + c];
}

// ---------------------------------------------------------------------------
// Mb = A0_dedup @ S0, gathering bf16 rows of S0h; f32 accumulate/output.
// ---------------------------------------------------------------------------
__global__ __launch_bounds__(256) void k_aggM_bf16(
    const int* __restrict__ offsets, const int* __restrict__ csr,
    const unsigned short* __restrict__ S0h, float* __restrict__ Mb)
{
  int j = blockIdx.x;
  int beg = offsets[j], deg = offsets[j + 1] - beg;
  __shared__ int srcs[512];
  bool inl = (deg <= 512);
  if (inl) for (int i = threadIdx.x; i < deg; i += 256) srcs[i] = csr[beg + i];
  __syncthreads();
  if (inl) {
    for (int t = threadIdx.x; t < deg; t += 256) {
      int v = srcs[t];
      for (int u = 0; u < t; ++u)
        if (csr[beg + u] == v) { srcs[t] = -1; break; }
    }
  }
  __syncthreads();
  int c2 = threadIdx.x;  // owns cols 2*c2, 2*c2+1
  float a0 = 0.f, a1 = 0.f;
  for (int i = 0; i < deg; i++) {
    int s = inl ? srcs[i] : csr[beg + i];
    if (!inl) {
      bool dup = false;
      for (int u = 0; u < i; u++) if (csr[beg + u] == s) { dup = true; break; }
      if (dup) s = -1;
    }
    if (s >= 0) {
      ushort2 v = *(const ushort2*)(S0h + (size_t)s * P0C + c2 * 2);
      a0 += b2f(v.x); a1 += b2f(v.y);
    }
  }
  *(float2*)(Mb + (size_t)j * P0C + c2 * 2) = make_float2(a0, a1);
}

// ---------------------------------------------------------------------------
// Fused expmap0/logmap0 row scale
// ---------------------------------------------------------------------------
__global__ __launch_bounds__(256) void k_rowscale(const float* __restrict__ U, int cols,
                                                  float* __restrict__ rs)
{
  int r = blockIdx.x;
  const float* row = U + (size_t)r * cols;
  float ss = 0.f;
  for (int c = threadIdx.x; c < cols; c += 256) { float v = row[c]; ss += v * v; }
  for (int off = 32; off > 0; off >>= 1) ss += __shfl_down(ss, off);
  __shared__ float red[4];
  if ((threadIdx.x & 63) == 0) red[threadIdx.x >> 6] = ss;
  __syncthreads();
  if (threadIdx.x == 0) {
    float n = sqrtf(red[0] + red[1] + red[2] + red[3]);
    n = fmaxf(n, 1e-15f);
    rs[r] = TEMPC * fminf(n, ATANH_MAX) / n;
  }
}

// ---------------------------------------------------------------------------
// Column softmax (axis=0), two-stage online
// ---------------------------------------------------------------------------
__global__ __launch_bounds__(256) void k_smaxA(const float* __restrict__ U,
    const float* __restrict__ rs, float* __restrict__ pm, float* __restrict__ ps,
    int rows, int cols, int rpg)
{
  int lc = threadIdx.x & 63;
  int c = blockIdx.x * 64 + lc;
  int rl = threadIdx.x >> 6;
  int r0 = blockIdx.y * rpg, r1 = min(rows, r0 + rpg);
  float m = -1e30f, s = 0.f;
  for (int r = r0 + rl; r < r1; r += 4) {
    float l = rs[r] * U[(size_t)r * cols + c];
    if (l > m) { s = s * __expf(m - l) + 1.f; m = l; }
    else s += __expf(l - m);
  }
  __shared__ float sm[4][64], sv[4][64];
  sm[rl][lc] = m; sv[rl][lc] = s;
  __syncthreads();
  if (threadIdx.x < 64) {
    float mm = sm[0][threadIdx.x], s2 = sv[0][threadIdx.x];
    for (int q = 1; q < 4; q++) {
      float mq = sm[q][threadIdx.x], sq = sv[q][threadIdx.x];
      float mn = fmaxf(mm, mq);
      s2 = s2 * __expf(mm - mn) + sq * __expf(mq - mn);
      mm = mn;
    }
    pm[(size_t)blockIdx.y * cols + blockIdx.x * 64 + threadIdx.x] = mm;
    ps[(size_t)blockIdx.y * cols + blockIdx.x * 64 + threadIdx.x] = s2;
  }
}

__global__ void k_smaxB(const float* __restrict__ pm, const float* __restrict__ ps,
                        float* __restrict__ colm, float* __restrict__ colsum,
                        int ng, int cols)
{
  int c = blockIdx.x * blockDim.x + threadIdx.x;
  if (c >= cols) return;
  float m = -1e30f, s = 0.f;
  for (int g = 0; g < ng; g++) {
    float mg = pm[(size_t)g * cols + c], sg = ps[(size_t)g * cols + c];
    float mn = fmaxf(m, mg);
    s = s * __expf(m - mn) + sg * __expf(mg - mn);
    m = mn;
  }
  colm[c] = m; colsum[c] = s;
}

// writes f32 S0, bf16 S0h, and entropy
__global__ __launch_bounds__(256) void k_smaxC(const float* __restrict__ U,
    const float* __restrict__ rs, const float* __restrict__ colm,
    const float* __restrict__ colsum, float* __restrict__ S,
    unsigned short* __restrict__ Sh,
    float* __restrict__ loss, int rows, int cols, int rpg)
{
  int lc = threadIdx.x & 63;
  int c = blockIdx.x * 64 + lc;
  int rl = threadIdx.x >> 6;
  int r0 = blockIdx.y * rpg, r1 = min(rows, r0 + rpg);
  float m = colm[c], inv = 1.f / colsum[c];
  float h = 0.f;
  for (int r = r0 + rl; r < r1; r += 4) {
    float l = rs[r] * U[(size_t)r * cols + c];
    float p = __expf(l - m) * inv;
    S[(size_t)r * cols + c] = p;
    Sh[(size_t)r * cols + c] = f2b(p);
    if (p > 0.f) h -= p * __logf(p);
  }
  for (int off = 32; off > 0; off >>= 1) h += __shfl_down(h, off);
  __shared__ float red[4];
  if ((threadIdx.x & 63) == 0) red[threadIdx.x >> 6] = h;
  __syncthreads();
  if (threadIdx.x == 0) atomicAdd(loss, red[0] + red[1] + red[2] + red[3]);
}

// single-stage small column softmax (level 1: 512 rows)
__global__ __launch_bounds__(256) void k_smax_small(const float* __restrict__ U,
    const float* __restrict__ rs, float* __restrict__ S, float* __restrict__ loss,
    int rows, int cols)
{
  int lc = threadIdx.x & 63;
  int c = blockIdx.x * 64 + lc;
  int rl = threadIdx.x >> 6;
  float m = -1e30f, s = 0.f;
  for (int r = rl; r < rows; r += 4) {
    float l = rs[r] * U[(size_t)r * cols + c];
    if (l > m) { s = s * __expf(m - l) + 1.f; m = l; }
    else s += __expf(l - m);
  }
  __shared__ float sm[4][64], sv[4][64], fm[64], fs[64];
  sm[rl][lc] = m; sv[rl][lc] = s;
  __syncthreads();
  if (threadIdx.x < 64) {
    float mm = sm[0][threadIdx.x], s2 = sv[0][threadIdx.x];
    for (int q = 1; q < 4; q++) {
      float mq = sm[q][threadIdx.x], sq = sv[q][threadIdx.x];
      float mn = fmaxf(mm, mq);
      s2 = s2 * __expf(mm - mn) + sq * __expf(mq - mn);
      mm = mn;
    }
    fm[threadIdx.x] = mm; fs[threadIdx.x] = s2;
  }
  __syncthreads();
  float M0 = fm[lc], inv = 1.f / fs[lc];
  float h = 0.f;
  for (int r = rl; r < rows; r += 4) {
    float l = rs[r] * U[(size_t)r * cols + c];
    float p = __expf(l - M0) * inv;
    S[(size_t)r * cols + c] = p;
    if (p > 0.f) h -= p * __logf(p);
  }
  for (int off = 32; off > 0; off >>= 1) h += __shfl_down(h, off);
  if ((threadIdx.x & 63) == 0) atomicAdd(loss, h);
}

// ---------------------------------------------------------------------------
// y-projection via split-K partials
// ---------------------------------------------------------------------------
__global__ __launch_bounds__(256) void k_yS_part(
    const float* __restrict__ Y, int ldy,
    const float* __restrict__ S, int ldS,
    float* __restrict__ part, int K, int C, int kchunk)
{
  int lc = threadIdx.x & 63;
  int c = blockIdx.x * 64 + lc;
  int rl = threadIdx.x >> 6;
  int r0 = blockIdx.y * kchunk, r1 = min(K, r0 + kchunk);
  float acc[8] = {};
  for (int r = r0 + rl; r < r1; r += 4) {
    float sv = S[(size_t)r * ldS + c];
#pragma unroll
    for (int t = 0; t < 8; t++) acc[t] += Y[(size_t)t * ldy + r] * sv;
  }
  __shared__ float red[4][8][64];
#pragma unroll
  for (int t = 0; t < 8; t++) red[rl][t][lc] = acc[t];
  __syncthreads();
  if (rl == 0) {
#pragma unroll
    for (int t = 0; t < 8; t++) {
      float v = red[0][t][lc] + red[1][t][lc] + red[2][t][lc] + red[3][t][lc];
      part[((size_t)blockIdx.y * 8 + t) * C + c] = v;
    }
  }
}

__global__ void k_yS_red(const float* __restrict__ part, float* __restrict__ outp,
                         int nparts, int sz)
{
  int idx = blockIdx.x * 256 + threadIdx.x;
  if (idx >= sz) return;
  float s = 0.f;
  for (int p = 0; p < nparts; ++p) s += part[(size_t)p * sz + idx];
  outp[idx] = s;
}

__global__ void k_zbuild1(const float* __restrict__ x1f, const float* __restrict__ zi1,
                          float* __restrict__ z1)
{
  int idx = blockIdx.x * 256 + threadIdx.x;
  if (idx >= P0C * DC) return;
  int r = idx >> 7, c = idx & 127;
  z1[idx] = (c < 8) ? x1f[idx] : zi1[r * ZIC + c - 8];
}

// f32 -> f32 copy/emit with independent src/dst leading dims
__global__ void k_emit(const float* __restrict__ src, int lsrc,
                       float* __restrict__ dst, int ldd, int rows, int cols)
{
  int idx = blockIdx.x * 256 + threadIdx.x;
  if (idx >= rows * cols) return;
  int r = idx / cols, c = idx - r * cols;
  dst[(size_t)r * ldd + c] = src[(size_t)r * lsrc + c];
}

// ---------------------------------------------------------------------------
extern "C" void kernel_launch(void* const* d_in, const int* in_sizes, int n_in,
                              void* d_out, int out_size, void* d_ws, size_t ws_size,
                              hipStream_t stream)
{
  (void)in_sizes; (void)n_in; (void)out_size; (void)ws_size;
  const float* x   = (const float*)d_in[0];
  const float* y   = (const float*)d_in[1];
  const float* We0 = (const float*)d_in[2];
  const float* be0 = (const float*)d_in[3];
  const float* Ws0 = (const float*)d_in[4];
  const float* bs0 = (const float*)d_in[5];
  const float* We1 = (const float*)d_in[6];
  const float* be1 = (const float*)d_in[7];
  const float* Ws1 = (const float*)d_in[8];
  const float* bs1 = (const float*)d_in[9];
  const int*   adj = (const int*)d_in[10];
  float* out = (float*)d_out;

  float* ws = (float*)d_ws;
  size_t o = 0;
  auto alloc = [&](size_t n) { float* p = ws + o; o += n; return p; };
  float* xa    = alloc((size_t)NC * DC);     // aggregated raw x
  float* sPre  = alloc((size_t)NC * P0C);    // reused as S0 after softmax
  float* sAgg  = alloc((size_t)NC * P0C);    // softmax logits src; then Mb; then A1 partials
  float* zbuf  = alloc((size_t)NC * DC);     // z; reused as x1 partials
  float* rsc   = alloc(NC);
  float* degf  = alloc(NC);
  float* pm    = alloc(32 * P0C);
  float* ps    = alloc(32 * P0C);
  float* colm  = alloc(P0C);
  float* colsum= alloc(P0C);
  float* t1    = alloc((size_t)P0C * ZIC);
  float* s1pre = alloc((size_t)P0C * P1C);
  float* zi1   = alloc((size_t)P0C * ZIC);
  float* s1agg = alloc((size_t)P0C * P1C);
  float* S1    = alloc((size_t)P0C * P1C);
  float* z1    = alloc((size_t)P0C * P1C);
  float* rs1   = alloc(P0C);
  float* x1f   = alloc((size_t)P0C * DC);
  float* A1    = alloc((size_t)P0C * P0C);
  unsigned short* S0T   = (unsigned short*)alloc((size_t)P0C * NC / 2); // 512x8192 bf16
  unsigned short* MbT   = (unsigned short*)alloc((size_t)P0C * NC / 2); // 512x8192 bf16
  unsigned short* zbufT = (unsigned short*)alloc((size_t)DC * NC / 2);  // 128x8192 bf16
  unsigned short* S0h   = (unsigned short*)alloc((size_t)NC * P0C / 2); // 8192x512 bf16 row-major
  float* partY1 = alloc((size_t)128 * TC * P0C);
  float* partY2 = alloc((size_t)8 * TC * P1C);
  float* partL1a = alloc((size_t)2 * P0C * ZIC);
  float* partL1b = alloc((size_t)2 * P0C * P1C);
  float* partL1c = alloc((size_t)8 * P0C * ZIC);
  float* partL1d = alloc((size_t)8 * P0C * P1C);
  // atomic-accumulated zone (contiguous, zeroed every call)
  float* x2f   = alloc((size_t)P1C * DC);
  float* y1f   = alloc((size_t)TC * P0C);
  float* y2f   = alloc((size_t)TC * P1C);
  float* lossf = alloc(1);
  size_t atomicFloats = (size_t)P1C*DC + (size_t)TC*P0C + (size_t)TC*P1C + 1;
  o = (o + 63) & ~(size_t)63;
  int* ibase   = (int*)(ws + o);
  int* counts  = ibase;
  int* fill    = ibase + NC;
  int* offsets = ibase + 2 * NC;
  int* csr     = ibase + 2 * NC + (NC + 1);

  float* S0 = sPre;        // softmax output
  float* Mb = sAgg;        // alias: sAgg (logits) dead after smaxC
  float* partsA1 = sAgg;   // alias: Mb dead after MbT transpose
  float* partsX1 = zbuf;   // alias: zbuf dead after zbufT transpose

  hipMemsetAsync(x2f, 0, atomicFloats * sizeof(float), stream);
  hipMemsetAsync(counts, 0, 2 * NC * sizeof(int), stream);

  // ---- CSR build + degree ----
  k_count  <<<EC/256, 256, 0, stream>>>(adj, counts);
  k_scan   <<<1, 1024, 0, stream>>>(counts, offsets);
  k_scatter<<<EC/256, 256, 0, stream>>>(adj, offsets, fill, csr);
  k_degf   <<<NC/256, 256, 0, stream>>>(counts, degf);

  // ---- aggregate raw x, then push through linear maps (exact) ----
  k_aggX<<<NC, 128, 0, stream>>>(offsets, csr, x, xa, zbuf);
  // sAgg = xa @ Ws0 + deg*bs0
  k_gemm_nn_degbias<<<dim3(NC/64, P0C/64), 256, 0, stream>>>(xa, DC, Ws0, P0C, bs0, degf, sAgg, P0C, NC, P0C, DC);
  // z[:, 8:] = xa[:, 8:] @ We0 + deg*be0
  k_gemm_nn_degbias<<<dim3(NC/64, 2), 256, 0, stream>>>(xa + 8, DC, We0, ZIC, be0, degf, zbuf + 8, DC, NC, ZIC, ZIC);
  k_transpose_bf16<<<dim3(NC/64, DC/64), 256, 0, stream>>>(zbuf, NC, DC, zbufT);

  // ---- fused expmap/logmap + column softmax -> S0 (f32 + bf16), entropy ----
  k_rowscale<<<NC, 256, 0, stream>>>(sAgg, P0C, rsc);
  k_smaxA<<<dim3(P0C/64, 32), 256, 0, stream>>>(sAgg, rsc, pm, ps, NC, P0C, 256);
  k_smaxB<<<P0C/256, 256, 0, stream>>>(pm, ps, colm, colsum, 32, P0C);
  k_smaxC<<<dim3(P0C/64, 32), 256, 0, stream>>>(sAgg, rsc, colm, colsum, S0, S0h, lossf, NC, P0C, 256);
  k_transpose_bf16<<<dim3(NC/64, P0C/64), 256, 0, stream>>>(S0, NC, P0C, S0T);

  // ---- Mb = A0_dedup @ S0 (bf16 gather) ; transpose ----
  k_aggM_bf16<<<NC, 256, 0, stream>>>(offsets, csr, S0h, Mb);
  k_transpose_bf16<<<dim3(NC/64, P0C/64), 256, 0, stream>>>(Mb, NC, P0C, MbT);

  // ---- pooled products via bf16 MFMA (split-K partials + reduce) ----
  k_nt_bf16<<<dim3(P0C/64, P0C/64, 8), 256, 0, stream>>>(S0T, MbT, partsA1, P0C, P0C, NC, 1024);
  k_reduce_parts<<<(P0C*P0C)/256, 256, 0, stream>>>(partsA1, A1, 8, P0C*P0C);
  k_nt_bf16<<<dim3(P0C/64, DC/64, 16), 256, 0, stream>>>(S0T, zbufT, partsX1, P0C, DC, NC, 512);
  k_reduce_parts<<<(P0C*DC)/256, 256, 0, stream>>>(partsX1, x1f, 16, P0C*DC);
  k_yS_part<<<dim3(P0C/64, 128), 256, 0, stream>>>(y, NC, S0, P0C, partY1, NC, P0C, 64);
  k_yS_red<<<(TC*P0C + 255)/256, 256, 0, stream>>>(partY1, y1f, 128, TC*P0C);

  // ---- level 1 (split-K f32) ----
  k_gemm_nn_part<<<dim3(P0C/64, 2, 2), 256, 0, stream>>>(x1f + 8, DC, We1, ZIC, partL1a, P0C, ZIC, ZIC, 64);
  k_reduce_bias<<<(P0C*ZIC + 255)/256, 256, 0, stream>>>(partL1a, be1, t1, 2, P0C, ZIC);
  k_gemm_nn_part<<<dim3(P0C/64, P1C/64, 2), 256, 0, stream>>>(x1f, DC, Ws1, P1C, partL1b, P0C, P1C, DC, 64);
  k_reduce_bias<<<(P0C*P1C + 255)/256, 256, 0, stream>>>(partL1b, bs1, s1pre, 2, P0C, P1C);
  k_gemm_nn_part<<<dim3(P0C/64, 2, 8), 256, 0, stream>>>(A1, P0C, t1, ZIC, partL1c, P0C, ZIC, P0C, 64);
  k_reduce_bias<<<(P0C*ZIC + 255)/256, 256, 0, stream>>>(partL1c, nullptr, zi1, 8, P0C, ZIC);
  k_gemm_nn_part<<<dim3(P0C/64, P1C/64, 8), 256, 0, stream>>>(A1, P0C, s1pre, P1C, partL1d, P0C, P1C, P0C, 64);
  k_reduce_bias<<<(P0C*P1C + 255)/256, 256, 0, stream>>>(partL1d, nullptr, s1agg, 8, P0C, P1C);

  k_zbuild1<<<(P0C*DC + 255)/256, 256, 0, stream>>>(x1f, zi1, z1);
  k_rowscale<<<P0C, 256, 0, stream>>>(s1agg, P1C, rs1);
  k_smax_small<<<P1C/64, 256, 0, stream>>>(s1agg, rs1, S1, lossf, P0C, P1C);
  k_gemm_tn<<<dim3(P1C/64, DC/64, 4), 256, 0, stream>>>(S1, P1C, z1, DC, x2f, DC, P1C, DC, P0C, 128);
  k_yS_part<<<dim3(P1C/64, 8), 256, 0, stream>>>(y1f, P0C, S1, P1C, partY2, P0C, P1C, 64);
  k_yS_red<<<(TC*P1C + 255)/256, 256, 0, stream>>>(partY2, y2f, 8, TC*P1C);

  // ---- emit outputs (f32) ----
  const size_t yr_off = (size_t)(NC + P0C + P1C) * DC;  // 1130496
  const int YW = NC + P0C + P1C;                        // 8832
  k_emit<<<(NC*DC + 255)/256, 256, 0, stream>>>(x, DC, out, DC, NC, DC);
  k_emit<<<(P0C*DC + 255)/256, 256, 0, stream>>>(x1f, DC, out + (size_t)NC*DC, DC, P0C, DC);
  k_emit<<<(P1C*DC + 255)/256, 256, 0, stream>>>(x2f, DC, out + (size_t)(NC+P0C)*DC, DC, P1C, DC);
  k_emit<<<(TC*NC + 255)/256, 256, 0, stream>>>(y, NC, out + yr_off, YW, TC, NC);
  k_emit<<<(TC*P0C + 255)/256, 256, 0, stream>>>(y1f, P0C, out + yr_off + NC, YW, TC, P0C);
  k_emit<<<(TC*P1C + 255)/256, 256, 0, stream>>>(y2f, P1C, out + yr_off + NC + P0C, YW, TC, P1C);
  k_emit<<<1, 256, 0, stream>>>(lossf, 1, out + yr_off + (size_t)TC*YW, 1, 1, 1);
}

// Round 7
// 414.594 us; speedup vs baseline: 2.5722x; 1.1722x over previous
//
#include <hip/hip_runtime.h>
#include <hip/hip_bf16.h>

// Problem constants
#define NC   8192
#define EC   131072
#define DC   128
#define TC   8
#define P0C  512
#define P1C  128
#define ZIC  120
#define TEMPC 200.0f
// atanh(float32(1 - 1e-5)) = atanh(0.99999004602432251) -- matches JAX's f32 clip
#define ATANH_MAX 6.1053405f

typedef short short8 __attribute__((ext_vector_type(8)));
typedef float f32x4 __attribute__((ext_vector_type(4)));

__device__ inline unsigned short f2b(float f) {  // f32 -> bf16 bits, RNE
  union { float f; unsigned u; } x; x.f = f;
  unsigned r = x.u + 0x7FFFu + ((x.u >> 16) & 1u);
  return (unsigned short)(r >> 16);
}
__device__ inline float b2f(unsigned short b) {
  union { unsigned u; float f; } x; x.u = ((unsigned)b) << 16; return x.f;
}

// ---------------------------------------------------------------------------
// Tiled f32 GEMM with deg-scaled bias:  C[M,N] = A@B + degf[m]*bias[n]
// ---------------------------------------------------------------------------
__global__ __launch_bounds__(256) void k_gemm_nn_degbias(
    const float* __restrict__ A, int lda,
    const float* __restrict__ B, int ldb,
    const float* __restrict__ bias,
    const float* __restrict__ degf,
    float* __restrict__ C, int ldc,
    int M, int N, int K)
{
  __shared__ float As[16][65];
  __shared__ float Bs[16][65];
  int bm = blockIdx.x * 64, bn = blockIdx.y * 64;
  int tid = threadIdx.x;
  int tm = (tid >> 4) << 2, tn = (tid & 15) << 2;
  float acc[4][4] = {};
  for (int k0 = 0; k0 < K; k0 += 16) {
    for (int i = tid; i < 1024; i += 256) {
      int m = i >> 4, k = i & 15;
      float v = 0.f;
      if (bm + m < M && k0 + k < K) v = A[(size_t)(bm + m) * lda + k0 + k];
      As[k][m] = v;
    }
    for (int i = tid; i < 1024; i += 256) {
      int k = i >> 6, n = i & 63;
      float v = 0.f;
      if (k0 + k < K && bn + n < N) v = B[(size_t)(k0 + k) * ldb + bn + n];
      Bs[k][n] = v;
    }
    __syncthreads();
#pragma unroll
    for (int kk = 0; kk < 16; ++kk) {
      float a[4], b[4];
#pragma unroll
      for (int i = 0; i < 4; i++) a[i] = As[kk][tm + i];
#pragma unroll
      for (int j = 0; j < 4; j++) b[j] = Bs[kk][tn + j];
#pragma unroll
      for (int i = 0; i < 4; i++)
#pragma unroll
        for (int j = 0; j < 4; j++) acc[i][j] += a[i] * b[j];
    }
    __syncthreads();
  }
#pragma unroll
  for (int i = 0; i < 4; i++) {
    int m = bm + tm + i; if (m >= M) continue;
    float dg = degf ? degf[m] : 1.f;
#pragma unroll
    for (int j = 0; j < 4; j++) {
      int n = bn + tn + j; if (n >= N) continue;
      float v = acc[i][j];
      if (bias) v += dg * bias[n];
      C[(size_t)m * ldc + n] = v;
    }
  }
}

// ---------------------------------------------------------------------------
// f32 NN GEMM, split-K partials (level-1 small GEMMs)
// ---------------------------------------------------------------------------
__global__ __launch_bounds__(256) void k_gemm_nn_part(
    const float* __restrict__ A, int lda,
    const float* __restrict__ B, int ldb,
    float* __restrict__ part,
    int M, int N, int K, int kchunk)
{
  __shared__ float As[16][65];
  __shared__ float Bs[16][65];
  int bm = blockIdx.x * 64, bn = blockIdx.y * 64;
  int z = blockIdx.z;
  int ks = z * kchunk, ke = min(K, ks + kchunk);
  int tid = threadIdx.x;
  int tm = (tid >> 4) << 2, tn = (tid & 15) << 2;
  float acc[4][4] = {};
  for (int k0 = ks; k0 < ke; k0 += 16) {
    for (int i = tid; i < 1024; i += 256) {
      int m = i >> 4, k = i & 15;
      float v = 0.f;
      if (bm + m < M && k0 + k < ke) v = A[(size_t)(bm + m) * lda + k0 + k];
      As[k][m] = v;
    }
    for (int i = tid; i < 1024; i += 256) {
      int k = i >> 6, n = i & 63;
      float v = 0.f;
      if (k0 + k < ke && bn + n < N) v = B[(size_t)(k0 + k) * ldb + bn + n];
      Bs[k][n] = v;
    }
    __syncthreads();
#pragma unroll
    for (int kk = 0; kk < 16; ++kk) {
      float a[4], b[4];
#pragma unroll
      for (int i = 0; i < 4; i++) a[i] = As[kk][tm + i];
#pragma unroll
      for (int j = 0; j < 4; j++) b[j] = Bs[kk][tn + j];
#pragma unroll
      for (int i = 0; i < 4; i++)
#pragma unroll
        for (int j = 0; j < 4; j++) acc[i][j] += a[i] * b[j];
    }
    __syncthreads();
  }
  size_t base = (size_t)z * M * N;
#pragma unroll
  for (int i = 0; i < 4; i++) {
    int m = bm + tm + i; if (m >= M) continue;
#pragma unroll
    for (int j = 0; j < 4; j++) {
      int n = bn + tn + j; if (n >= N) continue;
      part[base + (size_t)m * N + n] = acc[i][j];
    }
  }
}

__global__ void k_reduce_bias(const float* __restrict__ part,
                              const float* __restrict__ bias,
                              float* __restrict__ C, int nparts, int M, int N)
{
  int idx = blockIdx.x * 256 + threadIdx.x;
  if (idx >= M * N) return;
  int n = idx % N;
  float s = 0.f;
  for (int p = 0; p < nparts; ++p) s += part[(size_t)p * M * N + idx];
  if (bias) s += bias[n];
  C[idx] = s;
}

// ---------------------------------------------------------------------------
// Small f32 TN GEMM with split-K + atomics (x2 product)
// ---------------------------------------------------------------------------
__global__ __launch_bounds__(256) void k_gemm_tn(
    const float* __restrict__ A, int lda,
    const float* __restrict__ B, int ldb,
    float* __restrict__ C, int ldc,
    int M, int N, int K, int kchunk)
{
  __shared__ float As[16][65];
  __shared__ float Bs[16][65];
  int bm = blockIdx.x * 64, bn = blockIdx.y * 64;
  int ks = blockIdx.z * kchunk;
  int ke = min(K, ks + kchunk);
  int tid = threadIdx.x;
  int tm = (tid >> 4) << 2, tn = (tid & 15) << 2;
  float acc[4][4] = {};
  for (int k0 = ks; k0 < ke; k0 += 16) {
    for (int i = tid; i < 1024; i += 256) {
      int k = i >> 6, m = i & 63;
      float v = 0.f;
      if (k0 + k < ke && bm + m < M) v = A[(size_t)(k0 + k) * lda + bm + m];
      As[k][m] = v;
    }
    for (int i = tid; i < 1024; i += 256) {
      int k = i >> 6, n = i & 63;
      float v = 0.f;
      if (k0 + k < ke && bn + n < N) v = B[(size_t)(k0 + k) * ldb + bn + n];
      Bs[k][n] = v;
    }
    __syncthreads();
#pragma unroll
    for (int kk = 0; kk < 16; ++kk) {
      float a[4], b[4];
#pragma unroll
      for (int i = 0; i < 4; i++) a[i] = As[kk][tm + i];
#pragma unroll
      for (int j = 0; j < 4; j++) b[j] = Bs[kk][tn + j];
#pragma unroll
      for (int i = 0; i < 4; i++)
#pragma unroll
        for (int j = 0; j < 4; j++) acc[i][j] += a[i] * b[j];
    }
    __syncthreads();
  }
#pragma unroll
  for (int i = 0; i < 4; i++) {
    int m = bm + tm + i; if (m >= M) continue;
#pragma unroll
    for (int j = 0; j < 4; j++) {
      int n = bn + tn + j; if (n >= N) continue;
      atomicAdd(&C[(size_t)m * ldc + n], acc[i][j]);
    }
  }
}

// ---------------------------------------------------------------------------
// 64x64 f32 tile transpose + bf16 quantize: dst[c][r] = bf16(src[r][c])
// ---------------------------------------------------------------------------
__global__ __launch_bounds__(256) void k_transpose_bf16(
    const float* __restrict__ src, int R, int C,
    unsigned short* __restrict__ dst)
{
  __shared__ float tile[64][65];
  int br = blockIdx.x * 64, bc = blockIdx.y * 64;
  for (int idx = threadIdx.x; idx < 4096; idx += 256) {
    int r = idx >> 6, c = idx & 63;
    tile[r][c] = src[(size_t)(br + r) * C + bc + c];
  }
  __syncthreads();
  for (int idx = threadIdx.x; idx < 4096; idx += 256) {
    int c = idx >> 6, r = idx & 63;
    dst[(size_t)(bc + c) * R + br + r] = f2b(tile[r][c]);
  }
}

// ---------------------------------------------------------------------------
// bf16 MFMA NT GEMM: Cpart[z][M][N] = sum_k At[m][k]*Bt[n][k] over k-chunk z.
// ---------------------------------------------------------------------------
__global__ __launch_bounds__(256) void k_nt_bf16(
    const unsigned short* __restrict__ At,
    const unsigned short* __restrict__ Bt,
    float* __restrict__ Cpart,
    int M, int N, int K, int kchunk)
{
  __shared__ unsigned short Alds[64][136];
  __shared__ unsigned short Blds[64][136];
  const int bm = blockIdx.x * 64, bn = blockIdx.y * 64;
  const int z = blockIdx.z;
  const int k_beg = z * kchunk, k_end = k_beg + kchunk;
  const int tid = threadIdx.x;
  const int lane = tid & 63, wave = tid >> 6;
  const int lrow = lane & 15, lgrp = lane >> 4;
  f32x4 acc[4];
#pragma unroll
  for (int nt = 0; nt < 4; ++nt) acc[nt] = (f32x4){0.f, 0.f, 0.f, 0.f};

  for (int k0 = k_beg; k0 < k_end; k0 += 128) {
#pragma unroll
    for (int p = 0; p < 4; ++p) {
      int id = p * 256 + tid;
      int r = id >> 4;
      int c = id & 15;
      *(uint4*)(&Alds[r][c * 8]) =
          *(const uint4*)(At + (size_t)(bm + r) * K + k0 + c * 8);
      *(uint4*)(&Blds[r][c * 8]) =
          *(const uint4*)(Bt + (size_t)(bn + r) * K + k0 + c * 8);
    }
    __syncthreads();
#pragma unroll
    for (int kk = 0; kk < 4; ++kk) {
      short8 af = *(const short8*)(&Alds[wave * 16 + lrow][kk * 32 + lgrp * 8]);
#pragma unroll
      for (int nt = 0; nt < 4; ++nt) {
        short8 bf = *(const short8*)(&Blds[nt * 16 + lrow][kk * 32 + lgrp * 8]);
        acc[nt] = __builtin_amdgcn_mfma_f32_16x16x32_bf16(af, bf, acc[nt], 0, 0, 0);
      }
    }
    __syncthreads();
  }
  size_t base = (size_t)z * M * N;
#pragma unroll
  for (int nt = 0; nt < 4; ++nt) {
    int n = bn + nt * 16 + lrow;
#pragma unroll
    for (int r = 0; r < 4; ++r) {
      int m = bm + wave * 16 + lgrp * 4 + r;
      Cpart[base + (size_t)m * N + n] = acc[nt][r];
    }
  }
}

__global__ void k_reduce_parts(const float* __restrict__ part, float* __restrict__ C,
                               int nparts, int sz)
{
  int idx = blockIdx.x * 256 + threadIdx.x;
  if (idx >= sz) return;
  float s = 0.f;
  for (int p = 0; p < nparts; ++p) s += part[(size_t)p * sz + idx];
  C[idx] = s;
}

// ---------------------------------------------------------------------------
// CSR build
// ---------------------------------------------------------------------------
__global__ void k_count(const int* __restrict__ adj, int* __restrict__ counts)
{
  int e = blockIdx.x * 256 + threadIdx.x;
  if (e < EC) atomicAdd(&counts[adj[e]], 1);
}

__global__ __launch_bounds__(1024) void k_scan(const int* __restrict__ counts,
                                               int* __restrict__ offsets)
{
  __shared__ int tsum[1024];
  int tid = threadIdx.x;
  int base = tid * 8;
  int loc[8]; int s = 0;
#pragma unroll
  for (int i = 0; i < 8; i++) { loc[i] = s; s += counts[base + i]; }
  tsum[tid] = s;
  __syncthreads();
  for (int off = 1; off < 1024; off <<= 1) {
    int v = (tid >= off) ? tsum[tid - off] : 0;
    __syncthreads();
    tsum[tid] += v;
    __syncthreads();
  }
  int excl = (tid == 0) ? 0 : tsum[tid - 1];
#pragma unroll
  for (int i = 0; i < 8; i++) offsets[base + i] = excl + loc[i];
  if (tid == 1023) offsets[NC] = tsum[1023];
}

__global__ void k_scatter(const int* __restrict__ adj, const int* __restrict__ offsets,
                          int* __restrict__ fill, int* __restrict__ csr)
{
  int e = blockIdx.x * 256 + threadIdx.x;
  if (e < EC) {
    int d = adj[e], s = adj[EC + e];
    int p = atomicAdd(&fill[d], 1);
    csr[offsets[d] + p] = s;
  }
}

__global__ void k_degf(const int* __restrict__ counts, float* __restrict__ degf)
{
  int i = blockIdx.x * 256 + threadIdx.x;
  if (i < NC) degf[i] = (float)counts[i];
}

// ---------------------------------------------------------------------------
// Aggregate raw x rows (with multiplicity): xa[j,:] = sum_{e: dst=j} x[src_e,:]
// ---------------------------------------------------------------------------
__global__ __launch_bounds__(128) void k_aggX(
    const int* __restrict__ offsets, const int* __restrict__ csr,
    const float* __restrict__ x,
    float* __restrict__ xa, float* __restrict__ z)
{
  int j = blockIdx.x;
  int beg = offsets[j], deg = offsets[j + 1] - beg;
  __shared__ int srcs[512];
  bool inl = (deg <= 512);
  if (inl) for (int i = threadIdx.x; i < deg; i += 128) srcs[i] = csr[beg + i];
  __syncthreads();
  int c = threadIdx.x;
  float acc = 0.f;
  for (int i = 0; i < deg; i++) {
    int s = inl ? srcs[i] : csr[beg + i];
    acc += x[(size_t)s * DC + c];
  }
  xa[(size_t)j * DC + c] = acc;
  if (c < 8) z[(size_t)j * DC + c] = x[(size_t)j * DC + c];
}

// ---------------------------------------------------------------------------
// Mb = A0_dedup @ S0, gathering bf16 rows of S0h; f32 accumulate/output.
// ---------------------------------------------------------------------------
__global__ __launch_bounds__(256) void k_aggM_bf16(
    const int* __restrict__ offsets, const int* __restrict__ csr,
    const unsigned short* __restrict__ S0h, float* __restrict__ Mb)
{
  int j = blockIdx.x;
  int beg = offsets[j], deg = offsets[j + 1] - beg;
  __shared__ int srcs[512];
  bool inl = (deg <= 512);
  if (inl) for (int i = threadIdx.x; i < deg; i += 256) srcs[i] = csr[beg + i];
  __syncthreads();
  if (inl) {
    for (int t = threadIdx.x; t < deg; t += 256) {
      int v = srcs[t];
      for (int u = 0; u < t; ++u)
        if (csr[beg + u] == v) { srcs[t] = -1; break; }
    }
  }
  __syncthreads();
  int c2 = threadIdx.x;  // owns cols 2*c2, 2*c2+1
  float a0 = 0.f, a1 = 0.f;
  for (int i = 0; i < deg; i++) {
    int s = inl ? srcs[i] : csr[beg + i];
    if (!inl) {
      bool dup = false;
      for (int u = 0; u < i; u++) if (csr[beg + u] == s) { dup = true; break; }
      if (dup) s = -1;
    }
    if (s >= 0) {
      ushort2 v = *(const ushort2*)(S0h + (size_t)s * P0C + c2 * 2);
      a0 += b2f(v.x); a1 += b2f(v.y);
    }
  }
  *(float2*)(Mb + (size_t)j * P0C + c2 * 2) = make_float2(a0, a1);
}

// ---------------------------------------------------------------------------
// Fused expmap0/logmap0 row scale
// ---------------------------------------------------------------------------
__global__ __launch_bounds__(256) void k_rowscale(const float* __restrict__ U, int cols,
                                                  float* __restrict__ rs)
{
  int r = blockIdx.x;
  const float* row = U + (size_t)r * cols;
  float ss = 0.f;
  for (int c = threadIdx.x; c < cols; c += 256) { float v = row[c]; ss += v * v; }
  for (int off = 32; off > 0; off >>= 1) ss += __shfl_down(ss, off);
  __shared__ float red[4];
  if ((threadIdx.x & 63) == 0) red[threadIdx.x >> 6] = ss;
  __syncthreads();
  if (threadIdx.x == 0) {
    float n = sqrtf(red[0] + red[1] + red[2] + red[3]);
    n = fmaxf(n, 1e-15f);
    rs[r] = TEMPC * fminf(n, ATANH_MAX) / n;
  }
}

// ---------------------------------------------------------------------------
// Column softmax (axis=0) over 8192 rows, two-stage online
// ---------------------------------------------------------------------------
__global__ __launch_bounds__(256) void k_smaxA(const float* __restrict__ U,
    const float* __restrict__ rs, float* __restrict__ pm, float* __restrict__ ps,
    int rows, int cols, int rpg)
{
  int lc = threadIdx.x & 63;
  int c = blockIdx.x * 64 + lc;
  int rl = threadIdx.x >> 6;
  int r0 = blockIdx.y * rpg, r1 = min(rows, r0 + rpg);
  float m = -1e30f, s = 0.f;
  for (int r = r0 + rl; r < r1; r += 4) {
    float l = rs[r] * U[(size_t)r * cols + c];
    if (l > m) { s = s * __expf(m - l) + 1.f; m = l; }
    else s += __expf(l - m);
  }
  __shared__ float sm[4][64], sv[4][64];
  sm[rl][lc] = m; sv[rl][lc] = s;
  __syncthreads();
  if (threadIdx.x < 64) {
    float mm = sm[0][threadIdx.x], s2 = sv[0][threadIdx.x];
    for (int q = 1; q < 4; q++) {
      float mq = sm[q][threadIdx.x], sq = sv[q][threadIdx.x];
      float mn = fmaxf(mm, mq);
      s2 = s2 * __expf(mm - mn) + sq * __expf(mq - mn);
      mm = mn;
    }
    pm[(size_t)blockIdx.y * cols + blockIdx.x * 64 + threadIdx.x] = mm;
    ps[(size_t)blockIdx.y * cols + blockIdx.x * 64 + threadIdx.x] = s2;
  }
}

__global__ void k_smaxB(const float* __restrict__ pm, const float* __restrict__ ps,
                        float* __restrict__ colm, float* __restrict__ colsum,
                        int ng, int cols)
{
  int c = blockIdx.x * blockDim.x + threadIdx.x;
  if (c >= cols) return;
  float m = -1e30f, s = 0.f;
  for (int g = 0; g < ng; g++) {
    float mg = pm[(size_t)g * cols + c], sg = ps[(size_t)g * cols + c];
    float mn = fmaxf(m, mg);
    s = s * __expf(m - mn) + sg * __expf(mg - mn);
    m = mn;
  }
  colm[c] = m; colsum[c] = s;
}

// writes f32 S0, bf16 S0h, and entropy
__global__ __launch_bounds__(256) void k_smaxC(const float* __restrict__ U,
    const float* __restrict__ rs, const float* __restrict__ colm,
    const float* __restrict__ colsum, float* __restrict__ S,
    unsigned short* __restrict__ Sh,
    float* __restrict__ loss, int rows, int cols, int rpg)
{
  int lc = threadIdx.x & 63;
  int c = blockIdx.x * 64 + lc;
  int rl = threadIdx.x >> 6;
  int r0 = blockIdx.y * rpg, r1 = min(rows, r0 + rpg);
  float m = colm[c], inv = 1.f / colsum[c];
  float h = 0.f;
  for (int r = r0 + rl; r < r1; r += 4) {
    float l = rs[r] * U[(size_t)r * cols + c];
    float p = __expf(l - m) * inv;
    S[(size_t)r * cols + c] = p;
    Sh[(size_t)r * cols + c] = f2b(p);
    if (p > 0.f) h -= p * __logf(p);
  }
  for (int off = 32; off > 0; off >>= 1) h += __shfl_down(h, off);
  __shared__ float red[4];
  if ((threadIdx.x & 63) == 0) red[threadIdx.x >> 6] = h;
  __syncthreads();
  if (threadIdx.x == 0) atomicAdd(loss, red[0] + red[1] + red[2] + red[3]);
}

// ---------------------------------------------------------------------------
// Level-1 column softmax: one block per column, rows = 2*blockDim (512).
// Values held in registers; block reduce via shuffle + LDS; one atomic/block.
// ---------------------------------------------------------------------------
__global__ __launch_bounds__(256) void k_smax_col(const float* __restrict__ U,
    const float* __restrict__ rs, float* __restrict__ S, float* __restrict__ loss,
    int rows, int cols)
{
  int c = blockIdx.x;
  int tid = threadIdx.x;
  int r0 = tid, r1 = tid + 256;
  float v0 = rs[r0] * U[(size_t)r0 * cols + c];
  float v1 = rs[r1] * U[(size_t)r1 * cols + c];
  float m = fmaxf(v0, v1);
  for (int off = 32; off > 0; off >>= 1) m = fmaxf(m, __shfl_xor(m, off));
  __shared__ float red[4];
  if ((tid & 63) == 0) red[tid >> 6] = m;
  __syncthreads();
  m = fmaxf(fmaxf(red[0], red[1]), fmaxf(red[2], red[3]));
  float e0 = __expf(v0 - m), e1 = __expf(v1 - m);
  float s = e0 + e1;
  for (int off = 32; off > 0; off >>= 1) s += __shfl_xor(s, off);
  __syncthreads();
  __shared__ float red2[4];
  if ((tid & 63) == 0) red2[tid >> 6] = s;
  __syncthreads();
  s = red2[0] + red2[1] + red2[2] + red2[3];
  float inv = 1.f / s;
  float p0 = e0 * inv, p1 = e1 * inv;
  S[(size_t)r0 * cols + c] = p0;
  S[(size_t)r1 * cols + c] = p1;
  float h = 0.f;
  if (p0 > 0.f) h -= p0 * __logf(p0);
  if (p1 > 0.f) h -= p1 * __logf(p1);
  for (int off = 32; off > 0; off >>= 1) h += __shfl_xor(h, off);
  __syncthreads();
  __shared__ float red3[4];
  if ((tid & 63) == 0) red3[tid >> 6] = h;
  __syncthreads();
  if (tid == 0) atomicAdd(loss, red3[0] + red3[1] + red3[2] + red3[3]);
}

// ---------------------------------------------------------------------------
// y-projection via split-K partials
// ---------------------------------------------------------------------------
__global__ __launch_bounds__(256) void k_yS_part(
    const float* __restrict__ Y, int ldy,
    const float* __restrict__ S, int ldS,
    float* __restrict__ part, int K, int C, int kchunk)
{
  int lc = threadIdx.x & 63;
  int c = blockIdx.x * 64 + lc;
  int rl = threadIdx.x >> 6;
  int r0 = blockIdx.y * kchunk, r1 = min(K, r0 + kchunk);
  float acc[8] = {};
  for (int r = r0 + rl; r < r1; r += 4) {
    float sv = S[(size_t)r * ldS + c];
#pragma unroll
    for (int t = 0; t < 8; t++) acc[t] += Y[(size_t)t * ldy + r] * sv;
  }
  __shared__ float red[4][8][64];
#pragma unroll
  for (int t = 0; t < 8; t++) red[rl][t][lc] = acc[t];
  __syncthreads();
  if (rl == 0) {
#pragma unroll
    for (int t = 0; t < 8; t++) {
      float v = red[0][t][lc] + red[1][t][lc] + red[2][t][lc] + red[3][t][lc];
      part[((size_t)blockIdx.y * 8 + t) * C + c] = v;
    }
  }
}

__global__ void k_yS_red(const float* __restrict__ part, float* __restrict__ outp,
                         int nparts, int sz)
{
  int idx = blockIdx.x * 256 + threadIdx.x;
  if (idx >= sz) return;
  float s = 0.f;
  for (int p = 0; p < nparts; ++p) s += part[(size_t)p * sz + idx];
  outp[idx] = s;
}

__global__ void k_zbuild1(const float* __restrict__ x1f, const float* __restrict__ zi1,
                          float* __restrict__ z1)
{
  int idx = blockIdx.x * 256 + threadIdx.x;
  if (idx >= P0C * DC) return;
  int r = idx >> 7, c = idx & 127;
  z1[idx] = (c < 8) ? x1f[idx] : zi1[r * ZIC + c - 8];
}

// f32 -> f32 copy/emit with independent src/dst leading dims
__global__ void k_emit(const float* __restrict__ src, int lsrc,
                       float* __restrict__ dst, int ldd, int rows, int cols)
{
  int idx = blockIdx.x * 256 + threadIdx.x;
  if (idx >= rows * cols) return;
  int r = idx / cols, c = idx - r * cols;
  dst[(size_t)r * ldd + c] = src[(size_t)r * lsrc + c];
}

// ---------------------------------------------------------------------------
extern "C" void kernel_launch(void* const* d_in, const int* in_sizes, int n_in,
                              void* d_out, int out_size, void* d_ws, size_t ws_size,
                              hipStream_t stream)
{
  (void)in_sizes; (void)n_in; (void)out_size; (void)ws_size;
  const float* x   = (const float*)d_in[0];
  const float* y   = (const float*)d_in[1];
  const float* We0 = (const float*)d_in[2];
  const float* be0 = (const float*)d_in[3];
  const float* Ws0 = (const float*)d_in[4];
  const float* bs0 = (const float*)d_in[5];
  const float* We1 = (const float*)d_in[6];
  const float* be1 = (const float*)d_in[7];
  const float* Ws1 = (const float*)d_in[8];
  const float* bs1 = (const float*)d_in[9];
  const int*   adj = (const int*)d_in[10];
  float* out = (float*)d_out;

  float* ws = (float*)d_ws;
  size_t o = 0;
  auto alloc = [&](size_t n) { float* p = ws + o; o += n; return p; };
  float* xa    = alloc((size_t)NC * DC);
  float* sPre  = alloc((size_t)NC * P0C);    // S0 after softmax
  float* sAgg  = alloc((size_t)NC * P0C);    // logits; then Mb; then A1 partials
  float* zbuf  = alloc((size_t)NC * DC);     // z; reused as x1 partials
  float* rsc   = alloc(NC);
  float* degf  = alloc(NC);
  float* pm    = alloc(32 * P0C);
  float* ps    = alloc(32 * P0C);
  float* colm  = alloc(P0C);
  float* colsum= alloc(P0C);
  float* t1    = alloc((size_t)P0C * ZIC);
  float* s1pre = alloc((size_t)P0C * P1C);
  float* zi1   = alloc((size_t)P0C * ZIC);
  float* s1agg = alloc((size_t)P0C * P1C);
  float* S1    = alloc((size_t)P0C * P1C);
  float* z1    = alloc((size_t)P0C * P1C);
  float* rs1   = alloc(P0C);
  float* x1f   = alloc((size_t)P0C * DC);
  float* A1    = alloc((size_t)P0C * P0C);
  unsigned short* S0T   = (unsigned short*)alloc((size_t)P0C * NC / 2);
  unsigned short* MbT   = (unsigned short*)alloc((size_t)P0C * NC / 2);
  unsigned short* zbufT = (unsigned short*)alloc((size_t)DC * NC / 2);
  unsigned short* S0h   = (unsigned short*)alloc((size_t)NC * P0C / 2);
  float* partY1 = alloc((size_t)128 * TC * P0C);
  float* partY2 = alloc((size_t)8 * TC * P1C);
  float* partL1a = alloc((size_t)2 * P0C * ZIC);
  float* partL1b = alloc((size_t)2 * P0C * P1C);
  float* partL1c = alloc((size_t)8 * P0C * ZIC);
  float* partL1d = alloc((size_t)8 * P0C * P1C);
  // atomic-accumulated zone (contiguous, zeroed every call)
  float* x2f   = alloc((size_t)P1C * DC);
  float* y1f   = alloc((size_t)TC * P0C);
  float* y2f   = alloc((size_t)TC * P1C);
  float* lossf = alloc(1);
  size_t atomicFloats = (size_t)P1C*DC + (size_t)TC*P0C + (size_t)TC*P1C + 1;
  o = (o + 63) & ~(size_t)63;
  int* ibase   = (int*)(ws + o);
  int* counts  = ibase;
  int* fill    = ibase + NC;
  int* offsets = ibase + 2 * NC;
  int* csr     = ibase + 2 * NC + (NC + 1);

  float* S0 = sPre;
  float* Mb = sAgg;
  float* partsA1 = sAgg;
  float* partsX1 = zbuf;

  hipMemsetAsync(x2f, 0, atomicFloats * sizeof(float), stream);
  hipMemsetAsync(counts, 0, 2 * NC * sizeof(int), stream);

  // ---- CSR build + degree ----
  k_count  <<<EC/256, 256, 0, stream>>>(adj, counts);
  k_scan   <<<1, 1024, 0, stream>>>(counts, offsets);
  k_scatter<<<EC/256, 256, 0, stream>>>(adj, offsets, fill, csr);
  k_degf   <<<NC/256, 256, 0, stream>>>(counts, degf);

  // ---- aggregate raw x, then push through linear maps (exact) ----
  k_aggX<<<NC, 128, 0, stream>>>(offsets, csr, x, xa, zbuf);
  k_gemm_nn_degbias<<<dim3(NC/64, P0C/64), 256, 0, stream>>>(xa, DC, Ws0, P0C, bs0, degf, sAgg, P0C, NC, P0C, DC);
  k_gemm_nn_degbias<<<dim3(NC/64, 2), 256, 0, stream>>>(xa + 8, DC, We0, ZIC, be0, degf, zbuf + 8, DC, NC, ZIC, ZIC);
  k_transpose_bf16<<<dim3(NC/64, DC/64), 256, 0, stream>>>(zbuf, NC, DC, zbufT);

  // ---- fused expmap/logmap + column softmax -> S0 (f32 + bf16), entropy ----
  k_rowscale<<<NC, 256, 0, stream>>>(sAgg, P0C, rsc);
  k_smaxA<<<dim3(P0C/64, 32), 256, 0, stream>>>(sAgg, rsc, pm, ps, NC, P0C, 256);
  k_smaxB<<<P0C/256, 256, 0, stream>>>(pm, ps, colm, colsum, 32, P0C);
  k_smaxC<<<dim3(P0C/64, 32), 256, 0, stream>>>(sAgg, rsc, colm, colsum, S0, S0h, lossf, NC, P0C, 256);
  k_transpose_bf16<<<dim3(NC/64, P0C/64), 256, 0, stream>>>(S0, NC, P0C, S0T);

  // ---- Mb = A0_dedup @ S0 (bf16 gather) ; transpose ----
  k_aggM_bf16<<<NC, 256, 0, stream>>>(offsets, csr, S0h, Mb);
  k_transpose_bf16<<<dim3(NC/64, P0C/64), 256, 0, stream>>>(Mb, NC, P0C, MbT);

  // ---- pooled products via bf16 MFMA (split-K partials + reduce) ----
  k_nt_bf16<<<dim3(P0C/64, P0C/64, 8), 256, 0, stream>>>(S0T, MbT, partsA1, P0C, P0C, NC, 1024);
  k_reduce_parts<<<(P0C*P0C)/256, 256, 0, stream>>>(partsA1, A1, 8, P0C*P0C);
  k_nt_bf16<<<dim3(P0C/64, DC/64, 16), 256, 0, stream>>>(S0T, zbufT, partsX1, P0C, DC, NC, 512);
  k_reduce_parts<<<(P0C*DC)/256, 256, 0, stream>>>(partsX1, x1f, 16, P0C*DC);
  k_yS_part<<<dim3(P0C/64, 128), 256, 0, stream>>>(y, NC, S0, P0C, partY1, NC, P0C, 64);
  k_yS_red<<<(TC*P0C + 255)/256, 256, 0, stream>>>(partY1, y1f, 128, TC*P0C);

  // ---- level 1 (split-K f32) ----
  k_gemm_nn_part<<<dim3(P0C/64, 2, 2), 256, 0, stream>>>(x1f + 8, DC, We1, ZIC, partL1a, P0C, ZIC, ZIC, 64);
  k_reduce_bias<<<(P0C*ZIC + 255)/256, 256, 0, stream>>>(partL1a, be1, t1, 2, P0C, ZIC);
  k_gemm_nn_part<<<dim3(P0C/64, P1C/64, 2), 256, 0, stream>>>(x1f, DC, Ws1, P1C, partL1b, P0C, P1C, DC, 64);
  k_reduce_bias<<<(P0C*P1C + 255)/256, 256, 0, stream>>>(partL1b, bs1, s1pre, 2, P0C, P1C);
  k_gemm_nn_part<<<dim3(P0C/64, 2, 8), 256, 0, stream>>>(A1, P0C, t1, ZIC, partL1c, P0C, ZIC, P0C, 64);
  k_reduce_bias<<<(P0C*ZIC + 255)/256, 256, 0, stream>>>(partL1c, nullptr, zi1, 8, P0C, ZIC);
  k_gemm_nn_part<<<dim3(P0C/64, P1C/64, 8), 256, 0, stream>>>(A1, P0C, s1pre, P1C, partL1d, P0C, P1C, P0C, 64);
  k_reduce_bias<<<(P0C*P1C + 255)/256, 256, 0, stream>>>(partL1d, nullptr, s1agg, 8, P0C, P1C);

  k_zbuild1<<<(P0C*DC + 255)/256, 256, 0, stream>>>(x1f, zi1, z1);
  k_rowscale<<<P0C, 256, 0, stream>>>(s1agg, P1C, rs1);
  k_smax_col<<<P1C, 256, 0, stream>>>(s1agg, rs1, S1, lossf, P0C, P1C);
  k_gemm_tn<<<dim3(P1C/64, DC/64, 16), 256, 0, stream>>>(S1, P1C, z1, DC, x2f, DC, P1C, DC, P0C, 32);
  k_yS_part<<<dim3(P1C/64, 8), 256, 0, stream>>>(y1f, P0C, S1, P1C, partY2, P0C, P1C, 64);
  k_yS_red<<<(TC*P1C + 255)/256, 256, 0, stream>>>(partY2, y2f, 8, TC*P1C);

  // ---- emit outputs (f32) ----
  const size_t yr_off = (size_t)(NC + P0C + P1C) * DC;  // 1130496
  const int YW = NC + P0C + P1C;                        // 8832
  k_emit<<<(NC*DC + 255)/256, 256, 0, stream>>>(x, DC, out, DC, NC, DC);
  k_emit<<<(P0C*DC + 255)/256, 256, 0, stream>>>(x1f, DC, out + (size_t)NC*DC, DC, P0C, DC);
  k_emit<<<(P1C*DC + 255)/256, 256, 0, stream>>>(x2f, DC, out + (size_t)(NC+P0C)*DC, DC, P1C, DC);
  k_emit<<<(TC*NC + 255)/256, 256, 0, stream>>>(y, NC, out + yr_off, YW, TC, NC);
  k_emit<<<(TC*P0C + 255)/256, 256, 0, stream>>>(y1f, P0C, out + yr_off + NC, YW, TC, P0C);
  k_emit<<<(TC*P1C + 255)/256, 256, 0, stream>>>(y2f, P1C, out + yr_off + NC + P0C, YW, TC, P1C);
  k_emit<<<1, 256, 0, stream>>>(lossf, 1, out + yr_off + (size_t)TC*YW, 1, 1, 1);
}